// Round 17
// baseline (438.541 us; speedup 1.0000x reference)
//
#include <hip/hip_runtime.h>
#include <math.h>

#define T_TOK 1024
#define H_DIM 2048
#define N_EXP 32
#define TOPK  4
#define F_DIM 768
#define FS_DIM 4096
#define FS_HALF 2048
#define H_HALF 1024

typedef __bf16 bf16;
typedef __attribute__((ext_vector_type(4))) __bf16 bf16x4;
typedef __attribute__((ext_vector_type(8))) __bf16 bf16x8;
typedef __attribute__((ext_vector_type(4))) float f32x4;

// raw barrier: drain ds ops (lgkm) but let global prefetch loads stay in
// flight across the barrier; sched_barrier(0) pins code motion at the BAR.
#define BAR() do {                                        \
    asm volatile("s_waitcnt lgkmcnt(0)" ::: "memory");    \
    __builtin_amdgcn_s_barrier();                         \
    __builtin_amdgcn_sched_barrier(0);                    \
  } while (0)

// XOR-swizzled LDS offset: rows are 32 bf16 = 64B.
__device__ __forceinline__ int swz(int row, int colB) {
  return row * 64 + (colB ^ (((row >> 2) & 3) << 4));
}

// ---------------- router: fp32 logits -> softmax -> top4 -> lists ----------------
__global__ __launch_bounds__(256) void router_kernel(
    const float* __restrict__ x, const float* __restrict__ rw,
    const float* __restrict__ sgw,
    float* __restrict__ topw, float* __restrict__ sg,
    int* __restrict__ counts, int* __restrict__ lists)
{
  int t = blockIdx.x; int tid = threadIdx.x;
  int lane = tid & 63, wave = tid >> 6;
  float acc[N_EXP];
  #pragma unroll
  for (int e = 0; e < N_EXP; e++) acc[e] = 0.f;
  float accs = 0.f;
  const float* xr = x + (size_t)t * H_DIM;
  for (int h = tid; h < H_DIM; h += 256) {
    float xv = xr[h];
    accs += xv * sgw[h];
    #pragma unroll
    for (int e = 0; e < N_EXP; e++) acc[e] += xv * rw[e * H_DIM + h];
  }
  __shared__ float red[4][N_EXP];
  __shared__ float reds[4];
  __shared__ float logits[N_EXP];
  #pragma unroll
  for (int e = 0; e < N_EXP; e++) {
    float v = acc[e];
    for (int off = 32; off; off >>= 1) v += __shfl_down(v, off, 64);
    if (lane == 0) red[wave][e] = v;
  }
  {
    float v = accs;
    for (int off = 32; off; off >>= 1) v += __shfl_down(v, off, 64);
    if (lane == 0) reds[wave] = v;
  }
  __syncthreads();
  if (tid < N_EXP) logits[tid] = red[0][tid] + red[1][tid] + red[2][tid] + red[3][tid];
  __syncthreads();
  if (tid == 0) {
    float m = -1e30f;
    #pragma unroll
    for (int e = 0; e < N_EXP; e++) m = fmaxf(m, logits[e]);
    float p[N_EXP];
    #pragma unroll
    for (int e = 0; e < N_EXP; e++) p[e] = expf(logits[e] - m);
    int ids[TOPK]; float vs[TOPK]; float wsum = 0.f;
    #pragma unroll
    for (int k = 0; k < TOPK; k++) {
      int best = 0; float bv = -1.f;
      for (int e = 0; e < N_EXP; e++) {
        if (p[e] > bv) { bv = p[e]; best = e; }
      }
      ids[k] = best; vs[k] = bv; wsum += bv; p[best] = -2.f;
    }
    float inv = 1.f / wsum;
    float sgs = reds[0] + reds[1] + reds[2] + reds[3];
    sg[t] = 1.f / (1.f + expf(-sgs));
    #pragma unroll
    for (int k = 0; k < TOPK; k++) {
      int slot = t * TOPK + k;
      topw[slot] = vs[k] * inv;
      int pos = atomicAdd(&counts[ids[k]], 1);
      lists[ids[k] * T_TOK + pos] = slot;
    }
  }
}

// ---------------- x -> bf16 (halves all downstream A-request bytes) ----------------
__global__ __launch_bounds__(256) void xcvt_kernel(
    const float* __restrict__ x, bf16* __restrict__ xb)
{
  size_t i = ((size_t)blockIdx.x * 256 + threadIdx.x) * 8;
  f32x4 a = *(const f32x4*)(x + i);
  f32x4 b = *(const f32x4*)(x + i + 4);
  bf16x8 o;
  #pragma unroll
  for (int j = 0; j < 4; j++) { o[j] = (bf16)a[j]; o[4 + j] = (bf16)b[j]; }
  *(bf16x8*)(xb + i) = o;
}

// ------- fused gate/up dual GEMM + SwiGLU, 64x128 tile, BK=32, 512 threads -------
// A sourced from bf16 xb (8B/thread raw copy, no cvt). Threads 0-255 stage Wg,
// 256-511 stage Wu. 2-deep register prefetch, swizzled LDS, one BAR per K-step.
__global__ __launch_bounds__(512) __attribute__((amdgpu_waves_per_eu(4, 4)))
void gateup_fused(
    const bf16* __restrict__ XB,
    const float* __restrict__ wg_, const float* __restrict__ wu_,
    const float* __restrict__ swg, const float* __restrict__ swu,
    bf16* __restrict__ act, bf16* __restrict__ acts,
    const int* __restrict__ lists, const int* __restrict__ counts,
    int n_shared, int sh_nfb, int actsN, int col_off)
{
  int id = blockIdx.x;
  bool gather = id >= n_shared;
  const float *Wg, *Wu; const int* lb = nullptr;
  int count, mt, fb, ldb, Nout; bf16* C;
  if (gather) {
    int g = id - n_shared;
    int j = g >> 3;
    int e = (g & 7) + 8 * (j / 96);   // expert e's 96 blocks share an XCD
    int rr = j % 96;
    mt = (rr / 6) * 64; fb = (rr % 6) * 128;
    count = counts[e]; lb = lists + e * T_TOK;
    Wg = wg_ + (size_t)e * H_DIM * F_DIM;
    Wu = wu_ + (size_t)e * H_DIM * F_DIM;
    ldb = F_DIM; Nout = F_DIM; C = act;
  } else {
    fb = (id % sh_nfb) * 128; mt = (id / sh_nfb) * 64;
    count = T_TOK; ldb = FS_DIM; Nout = actsN;
    Wg = swg + col_off; Wu = swu + col_off;
    C = acts;
  }
  if (mt >= count) return;

  __shared__ alignas(16) char sA [2][64 * 64];    // [64m][32k] bf16, swizzled
  __shared__ alignas(16) char sBg[2][128 * 64];   // [128n][32k] bf16, swizzled
  __shared__ alignas(16) char sBu[2][128 * 64];

  int tid = threadIdx.x;
  int lane = tid & 63, wid = tid >> 6;
  int wr = wid >> 2, wc = wid & 3;   // 2x4 waves, wave tile 32m x 32n
  int l15 = lane & 15, qB = (lane >> 4) << 4;

  // A staging: row = tid>>3 (0..63), 8B bf16 at elem col (tid&7)*4
  const bf16* aptr;
  {
    int r = mt + (tid >> 3);
    int rc = r < count ? r : count - 1;
    int tok = gather ? (lb[rc] >> 2) : rc;
    aptr = XB + (size_t)tok * H_DIM + ((tid & 7) << 2);
  }
  // B staging: thread half -> one matrix; 4n x 4k block each
  int t8 = tid & 255;
  int bng = t8 & 31;             // n-quad 0..31
  int bk4 = (t8 >> 5) << 2;      // k base 0,4,..,28
  const float* bptr = (tid < 256 ? Wg : Wu) + (size_t)bk4 * ldb + fb + bng * 4;
  char* bds = (tid < 256) ? &sBg[0][0] : &sBu[0][0];

  f32x4 accg[2][2], accu[2][2];
  #pragma unroll
  for (int m = 0; m < 2; m++)
    #pragma unroll
    for (int n = 0; n < 2; n++) {
      accg[m][n] = (f32x4){0.f,0.f,0.f,0.f};
      accu[m][n] = (f32x4){0.f,0.f,0.f,0.f};
    }

  uint2 ava, avb; f32x4 bva[4], bvb[4];

  #define GU_ISSUE(av, bv, k0) do {                                   \
    av = *(const uint2*)(aptr + (k0));                                \
    _Pragma("unroll")                                                 \
    for (int r_ = 0; r_ < 4; r_++)                                    \
      bv[r_] = *(const f32x4*)(bptr + (size_t)((k0) + r_) * ldb);     \
    __builtin_amdgcn_sched_barrier(0);                                \
  } while (0)

  #define GU_STAGE(b, av, bv) do {                                    \
    *(uint2*)(sA[b] + swz(tid >> 3, (tid & 7) << 3)) = av;            \
    _Pragma("unroll")                                                 \
    for (int i_ = 0; i_ < 4; i_++) {                                  \
      bf16x4 tb;                                                      \
      tb[0]=(bf16)bv[0][i_]; tb[1]=(bf16)bv[1][i_];                   \
      tb[2]=(bf16)bv[2][i_]; tb[3]=(bf16)bv[3][i_];                   \
      *(bf16x4*)(bds + (b) * (128 * 64) + swz(bng * 4 + i_, bk4 << 1)) = tb; \
    } } while (0)

  #define GU_MFMA(b) do {                                             \
    __builtin_amdgcn_s_setprio(1);                                    \
    bf16x8 af0 = *(const bf16x8*)(sA[b] + swz(wr * 32 + l15, qB));    \
    bf16x8 af1 = *(const bf16x8*)(sA[b] + swz(wr * 32 + 16 + l15, qB)); \
    _Pragma("unroll")                                                 \
    for (int n_ = 0; n_ < 2; n_++) {                                  \
      int rb = wc * 32 + n_ * 16 + l15;                               \
      bf16x8 bg = *(const bf16x8*)(sBg[b] + swz(rb, qB));             \
      bf16x8 bu = *(const bf16x8*)(sBu[b] + swz(rb, qB));             \
      accg[0][n_] = __builtin_amdgcn_mfma_f32_16x16x32_bf16(af0, bg, accg[0][n_], 0,0,0); \
      accg[1][n_] = __builtin_amdgcn_mfma_f32_16x16x32_bf16(af1, bg, accg[1][n_], 0,0,0); \
      accu[0][n_] = __builtin_amdgcn_mfma_f32_16x16x32_bf16(af0, bu, accu[0][n_], 0,0,0); \
      accu[1][n_] = __builtin_amdgcn_mfma_f32_16x16x32_bf16(af1, bu, accu[1][n_], 0,0,0); \
    }                                                                 \
    __builtin_amdgcn_s_setprio(0);                                    \
  } while (0)

  const int NT = H_DIM / 32;   // 64
  GU_ISSUE(ava, bva, 0);
  GU_ISSUE(avb, bvb, 32);
  GU_STAGE(0, ava, bva);
  GU_ISSUE(ava, bva, 64);
  BAR();
  for (int t = 0; t < NT; t += 2) {
    GU_MFMA(0);                                    // tile t
    GU_STAGE(1, avb, bvb);                         // tile t+1
    if (t + 3 < NT) GU_ISSUE(avb, bvb, (t + 3) * 32);
    BAR();
    GU_MFMA(1);                                    // tile t+1
    if (t + 2 < NT) {
      GU_STAGE(0, ava, bva);                       // tile t+2
      if (t + 4 < NT) GU_ISSUE(ava, bva, (t + 4) * 32);
    }
    BAR();
  }
  #undef GU_ISSUE
  #undef GU_STAGE
  #undef GU_MFMA

  #pragma unroll
  for (int m = 0; m < 2; m++) {
    #pragma unroll
    for (int q = 0; q < 4; q++) {
      int gr = mt + wr * 32 + m * 16 + (lane >> 4) * 4 + q;
      if (gr < count) {
        size_t rowo = (gather ? (size_t)lb[gr] : (size_t)gr) * Nout;
        #pragma unroll
        for (int n = 0; n < 2; n++) {
          float g = accg[m][n][q], u = accu[m][n][q];
          C[rowo + fb + wc * 32 + n * 16 + l15] =
              (bf16)(g / (1.f + __expf(-g)) * u);
        }
      }
    }
  }
}

// ------- shared-expert down-proj, 64x128 tile, BK=32 (round-13 engine) -------
__global__ __launch_bounds__(256, 4) void dn_shared(
    const bf16* __restrict__ acts, const float* __restrict__ swd,
    float* __restrict__ out, const float* __restrict__ sg,
    int lda_sh, int kd_sh, int swd_off, int accum)
{
  int id = blockIdx.x;
  int nb = (id & 15) * 128, mt = (id >> 4) * 64;
  const bf16* A = acts; int lda = lda_sh, Kd = kd_sh;
  const float* W = swd + (size_t)swd_off * H_DIM;

  __shared__ alignas(16) char sA[2][64 * 64];
  __shared__ alignas(16) char sB[2][128 * 64];

  int tid = threadIdx.x;
  int lane = tid & 63, wid = tid >> 6;
  int wr = wid >> 1, wc = wid & 1;
  int l15 = lane & 15, qB = (lane >> 4) << 4;
  int bng = tid & 31;
  int bk4 = (tid >> 5) << 2;

  const bf16* aptr = A + (size_t)(mt + (tid >> 2)) * lda + ((tid & 3) << 3);
  const float* bptr = W + (size_t)bk4 * H_DIM + nb + bng * 4;

  f32x4 acc[2][4];
  #pragma unroll
  for (int m = 0; m < 2; m++)
    #pragma unroll
    for (int n = 0; n < 4; n++)
      acc[m][n] = (f32x4){0.f,0.f,0.f,0.f};

  uint4 ava, avb; f32x4 bva[4], bvb[4];

  #define DN_ISSUE(av, bv, k0) do {                                   \
    av = *(const uint4*)(aptr + (k0));                                \
    _Pragma("unroll")                                                 \
    for (int r_ = 0; r_ < 4; r_++)                                    \
      bv[r_] = *(const f32x4*)(bptr + (size_t)((k0) + r_) * H_DIM);   \
    } while (0)

  #define DN_STAGE(b, av, bv) do {                                    \
    *(uint4*)(sA[b] + swz(tid >> 2, (tid & 3) << 4)) = av;            \
    _Pragma("unroll")                                                 \
    for (int i_ = 0; i_ < 4; i_++) {                                  \
      bf16x4 tb;                                                      \
      tb[0]=(bf16)bv[0][i_]; tb[1]=(bf16)bv[1][i_];                   \
      tb[2]=(bf16)bv[2][i_]; tb[3]=(bf16)bv[3][i_];                   \
      *(bf16x4*)(sB[b] + swz(bng * 4 + i_, bk4 << 1)) = tb;           \
    } } while (0)

  #define DN_MFMA(b) do {                                             \
    __builtin_amdgcn_s_setprio(1);                                    \
    bf16x8 af0 = *(const bf16x8*)(sA[b] + swz(wr * 32 + l15, qB));    \
    bf16x8 af1 = *(const bf16x8*)(sA[b] + swz(wr * 32 + 16 + l15, qB)); \
    _Pragma("unroll")                                                 \
    for (int n_ = 0; n_ < 4; n_++) {                                  \
      bf16x8 bb = *(const bf16x8*)(sB[b] + swz(wc * 64 + n_ * 16 + l15, qB)); \
      acc[0][n_] = __builtin_amdgcn_mfma_f32_16x16x32_bf16(af0, bb, acc[0][n_], 0,0,0); \
      acc[1][n_] = __builtin_amdgcn_mfma_f32_16x16x32_bf16(af1, bb, acc[1][n_], 0,0,0); \
    }                                                                 \
    __builtin_amdgcn_s_setprio(0);                                    \
  } while (0)

  const int NT = Kd / 32;
  DN_ISSUE(ava, bva, 0);
  DN_ISSUE(avb, bvb, 32);
  DN_STAGE(0, ava, bva);
  DN_ISSUE(ava, bva, 64);
  BAR();
  for (int t = 0; t < NT; t += 2) {
    DN_MFMA(0);
    DN_STAGE(1, avb, bvb);
    if (t + 3 < NT) DN_ISSUE(avb, bvb, (t + 3) * 32);
    BAR();
    DN_MFMA(1);
    if (t + 2 < NT) {
      DN_STAGE(0, ava, bva);
      if (t + 4 < NT) DN_ISSUE(ava, bva, (t + 4) * 32);
    }
    BAR();
  }
  #undef DN_ISSUE
  #undef DN_STAGE
  #undef DN_MFMA

  #pragma unroll
  for (int m = 0; m < 2; m++) {
    #pragma unroll
    for (int q = 0; q < 4; q++) {
      int gr = mt + wr * 32 + m * 16 + (lane >> 4) * 4 + q;
      #pragma unroll
      for (int n = 0; n < 4; n++) {
        int col = nb + wc * 64 + n * 16 + l15;
        if (!accum) out[(size_t)gr * H_DIM + col] = sg[gr] * acc[m][n][q];
        else        out[(size_t)gr * H_DIM + col] += sg[gr] * acc[m][n][q];
      }
    }
  }
}

// ------- expert down-proj, H/2 column pass, 64x128 tile (round-13 engine) -------
// writes dsloth[slot][H_HALF] (bf16, unscaled). colbase = 0 or 1024.
__global__ __launch_bounds__(256, 4) void dn_expert(
    const bf16* __restrict__ act, const float* __restrict__ wd_,
    bf16* __restrict__ dsloth,
    const int* __restrict__ lists, const int* __restrict__ counts,
    int colbase)
{
  int g = blockIdx.x;
  int j = g >> 3;
  int e = (g & 7) + 8 * (j >> 7);   // expert e's 128 blocks share an XCD
  int rr = j & 127;
  int nbl = (rr & 7) * 128;         // local col in [0, 1024)
  int mt = (rr >> 3) * 64;          // 16 mt slots (covers count <= 1024)
  int count = counts[e];
  const int* lb = lists + e * T_TOK;
  if (mt >= count) return;
  const float* W = wd_ + (size_t)e * F_DIM * H_DIM;

  __shared__ alignas(16) char sA[2][64 * 64];
  __shared__ alignas(16) char sB[2][128 * 64];

  int tid = threadIdx.x;
  int lane = tid & 63, wid = tid >> 6;
  int wr = wid >> 1, wc = wid & 1;
  int l15 = lane & 15, qB = (lane >> 4) << 4;
  int bng = tid & 31;
  int bk4 = (tid >> 5) << 2;

  const bf16* aptr;
  {
    int r = mt + (tid >> 2);
    int rc = r < count ? r : count - 1;
    aptr = act + (size_t)lb[rc] * F_DIM + ((tid & 3) << 3);
  }
  const float* bptr = W + (size_t)bk4 * H_DIM + colbase + nbl + bng * 4;

  f32x4 acc[2][4];
  #pragma unroll
  for (int m = 0; m < 2; m++)
    #pragma unroll
    for (int n = 0; n < 4; n++)
      acc[m][n] = (f32x4){0.f,0.f,0.f,0.f};

  uint4 ava, avb; f32x4 bva[4], bvb[4];

  #define DE_ISSUE(av, bv, k0) do {                                   \
    av = *(const uint4*)(aptr + (k0));                                \
    _Pragma("unroll")                                                 \
    for (int r_ = 0; r_ < 4; r_++)                                    \
      bv[r_] = *(const f32x4*)(bptr + (size_t)((k0) + r_) * H_DIM);   \
    } while (0)

  #define DE_STAGE(b, av, bv) do {                                    \
    *(uint4*)(sA[b] + swz(tid >> 2, (tid & 3) << 4)) = av;            \
    _Pragma("unroll")                                                 \
    for (int i_ = 0; i_ < 4; i_++) {                                  \
      bf16x4 tb;                                                      \
      tb[0]=(bf16)bv[0][i_]; tb[1]=(bf16)bv[1][i_];                   \
      tb[2]=(bf16)bv[2][i_]; tb[3]=(bf16)bv[3][i_];                   \
      *(bf16x4*)(sB[b] + swz(bng * 4 + i_, bk4 << 1)) = tb;           \
    } } while (0)

  #define DE_MFMA(b) do {                                             \
    __builtin_amdgcn_s_setprio(1);                                    \
    bf16x8 af0 = *(const bf16x8*)(sA[b] + swz(wr * 32 + l15, qB));    \
    bf16x8 af1 = *(const bf16x8*)(sA[b] + swz(wr * 32 + 16 + l15, qB)); \
    _Pragma("unroll")                                                 \
    for (int n_ = 0; n_ < 4; n_++) {                                  \
      bf16x8 bb = *(const bf16x8*)(sB[b] + swz(wc * 64 + n_ * 16 + l15, qB)); \
      acc[0][n_] = __builtin_amdgcn_mfma_f32_16x16x32_bf16(af0, bb, acc[0][n_], 0,0,0); \
      acc[1][n_] = __builtin_amdgcn_mfma_f32_16x16x32_bf16(af1, bb, acc[1][n_], 0,0,0); \
    }                                                                 \
    __builtin_amdgcn_s_setprio(0);                                    \
  } while (0)

  const int NT = F_DIM / 32;   // 24
  DE_ISSUE(ava, bva, 0);
  DE_ISSUE(avb, bvb, 32);
  DE_STAGE(0, ava, bva);
  DE_ISSUE(ava, bva, 64);
  BAR();
  for (int t = 0; t < NT; t += 2) {
    DE_MFMA(0);
    DE_STAGE(1, avb, bvb);
    if (t + 3 < NT) DE_ISSUE(avb, bvb, (t + 3) * 32);
    BAR();
    DE_MFMA(1);
    if (t + 2 < NT) {
      DE_STAGE(0, ava, bva);
      if (t + 4 < NT) DE_ISSUE(ava, bva, (t + 4) * 32);
    }
    BAR();
  }
  #undef DE_ISSUE
  #undef DE_STAGE
  #undef DE_MFMA

  #pragma unroll
  for (int m = 0; m < 2; m++) {
    #pragma unroll
    for (int q = 0; q < 4; q++) {
      int gr = mt + wr * 32 + m * 16 + (lane >> 4) * 4 + q;
      if (gr < count) {
        #pragma unroll
        for (int n = 0; n < 4; n++) {
          int col = nbl + wc * 64 + n * 16 + l15;
          dsloth[(size_t)lb[gr] * H_HALF + col] = (bf16)acc[m][n][q];
        }
      }
    }
  }
}

// ---------------- combine half: out[:, colbase:colbase+1024] += sum_k topw*dsloth ----
__global__ __launch_bounds__(256) void combine_half(
    const bf16* __restrict__ dsloth, const float* __restrict__ topw,
    float* __restrict__ out, int colbase)
{
  int t = blockIdx.x;
  int c = threadIdx.x * 4;
  float w0 = topw[t * 4 + 0], w1 = topw[t * 4 + 1];
  float w2 = topw[t * 4 + 2], w3 = topw[t * 4 + 3];
  bf16x4 a0 = *(const bf16x4*)&dsloth[(size_t)(t * 4 + 0) * H_HALF + c];
  bf16x4 a1 = *(const bf16x4*)&dsloth[(size_t)(t * 4 + 1) * H_HALF + c];
  bf16x4 a2 = *(const bf16x4*)&dsloth[(size_t)(t * 4 + 2) * H_HALF + c];
  bf16x4 a3 = *(const bf16x4*)&dsloth[(size_t)(t * 4 + 3) * H_HALF + c];
  f32x4 o = *(f32x4*)&out[(size_t)t * H_DIM + colbase + c];
  #pragma unroll
  for (int j = 0; j < 4; j++)
    o[j] += w0 * (float)a0[j] + w1 * (float)a1[j] + w2 * (float)a2[j]
          + w3 * (float)a3[j];
  *(f32x4*)&out[(size_t)t * H_DIM + colbase + c] = o;
}

extern "C" void kernel_launch(void* const* d_in, const int* in_sizes, int n_in,
                              void* d_out, int out_size, void* d_ws, size_t ws_size,
                              hipStream_t stream) {
  const float* x   = (const float*)d_in[0];
  const float* rw  = (const float*)d_in[1];
  const float* wg  = (const float*)d_in[2];
  const float* wu  = (const float*)d_in[3];
  const float* wd  = (const float*)d_in[4];
  const float* swg = (const float*)d_in[5];
  const float* swu = (const float*)d_in[6];
  const float* swd = (const float*)d_in[7];
  const float* sgw = (const float*)d_in[8];
  float* out = (float*)d_out;
  char* ws = (char*)d_ws;

  // ws total ~23.2 MB (safe: 27.4 passed repeatedly; 34 MB overflowed in r3)
  size_t off = 0;
  int*   counts = (int*)(ws + off); off += 256;
  int*   lists  = (int*)(ws + off); off += (size_t)N_EXP * T_TOK * 4;
  float* topw   = (float*)(ws + off); off += (size_t)T_TOK * TOPK * 4;
  float* sg     = (float*)(ws + off); off += (size_t)T_TOK * 4;
  bf16*  xb     = (bf16*)(ws + off); off += (size_t)T_TOK * H_DIM * 2;          // 4.2 MB
  bf16*  act    = (bf16*)(ws + off); off += (size_t)T_TOK * TOPK * F_DIM * 2;   // 6.3 MB
  bf16*  acts   = (bf16*)(ws + off); off += (size_t)T_TOK * FS_HALF * 2;        // 4.2 MB
  bf16*  dsloth = (bf16*)(ws + off); off += (size_t)T_TOK * TOPK * H_HALF * 2;  // 8.4 MB

  hipMemsetAsync(counts, 0, 256, stream);

  router_kernel<<<T_TOK, 256, 0, stream>>>(x, rw, sgw, topw, sg, counts, lists);
  xcvt_kernel<<<(T_TOK * H_DIM) / 2048, 256, 0, stream>>>(x, xb);

  const int SH_NFB = FS_HALF / 128;            // 16
  const int NSH_GU = SH_NFB * (T_TOK / 64);    // 256
  const int EXP_GU = N_EXP * 96;               // 3072

  // gate/up: experts + shared FS half 0
  gateup_fused<<<NSH_GU + EXP_GU, 512, 0, stream>>>(
      xb, wg, wu, swg, swu, act, acts, lists, counts,
      NSH_GU, SH_NFB, FS_HALF, 0);
  // shared down half 0 (out =)
  dn_shared<<<256, 256, 0, stream>>>(acts, swd, out, sg, FS_HALF, FS_HALF, 0, 0);
  // shared gate/up FS half 1 (reuses acts)
  gateup_fused<<<NSH_GU, 512, 0, stream>>>(
      xb, wg, wu, swg, swu, act, acts, lists, counts,
      NSH_GU, SH_NFB, FS_HALF, FS_HALF);
  // shared down half 1 (out +=)
  dn_shared<<<256, 256, 0, stream>>>(acts, swd, out, sg, FS_HALF, FS_HALF, FS_HALF, 1);

  // expert down + combine, H column halves (reuse dsloth)
  dn_expert<<<N_EXP * 128, 256, 0, stream>>>(act, wd, dsloth, lists, counts, 0);
  combine_half<<<T_TOK, 256, 0, stream>>>(dsloth, topw, out, 0);
  dn_expert<<<N_EXP * 128, 256, 0, stream>>>(act, wd, dsloth, lists, counts, H_HALF);
  combine_half<<<T_TOK, 256, 0, stream>>>(dsloth, topw, out, H_HALF);
}

// Round 18
// 428.632 us; speedup vs baseline: 1.0231x; 1.0231x over previous
//
#include <hip/hip_runtime.h>
#include <math.h>

#define T_TOK 1024
#define H_DIM 2048
#define N_EXP 32
#define TOPK  4
#define F_DIM 768
#define FS_DIM 4096
#define FS_HALF 2048

typedef __bf16 bf16;
typedef __attribute__((ext_vector_type(4))) __bf16 bf16x4;
typedef __attribute__((ext_vector_type(8))) __bf16 bf16x8;
typedef __attribute__((ext_vector_type(4))) float f32x4;

// raw barrier: drain ds ops (lgkm) but let global prefetch loads stay in
// flight across the barrier; sched_barrier(0) pins code motion at the BAR.
#define BAR() do {                                        \
    asm volatile("s_waitcnt lgkmcnt(0)" ::: "memory");    \
    __builtin_amdgcn_s_barrier();                         \
    __builtin_amdgcn_sched_barrier(0);                    \
  } while (0)

// XOR-swizzled LDS offset: rows are 32 bf16 = 64B.
__device__ __forceinline__ int swz(int row, int colB) {
  return row * 64 + (colB ^ (((row >> 2) & 3) << 4));
}

// ---------------- router: fp32 logits -> softmax -> top4 -> lists ----------------
__global__ __launch_bounds__(256) void router_kernel(
    const float* __restrict__ x, const float* __restrict__ rw,
    const float* __restrict__ sgw,
    float* __restrict__ topw, float* __restrict__ sg,
    int* __restrict__ counts, int* __restrict__ lists)
{
  int t = blockIdx.x; int tid = threadIdx.x;
  int lane = tid & 63, wave = tid >> 6;
  float acc[N_EXP];
  #pragma unroll
  for (int e = 0; e < N_EXP; e++) acc[e] = 0.f;
  float accs = 0.f;
  const float* xr = x + (size_t)t * H_DIM;
  for (int h = tid; h < H_DIM; h += 256) {
    float xv = xr[h];
    accs += xv * sgw[h];
    #pragma unroll
    for (int e = 0; e < N_EXP; e++) acc[e] += xv * rw[e * H_DIM + h];
  }
  __shared__ float red[4][N_EXP];
  __shared__ float reds[4];
  __shared__ float logits[N_EXP];
  #pragma unroll
  for (int e = 0; e < N_EXP; e++) {
    float v = acc[e];
    for (int off = 32; off; off >>= 1) v += __shfl_down(v, off, 64);
    if (lane == 0) red[wave][e] = v;
  }
  {
    float v = accs;
    for (int off = 32; off; off >>= 1) v += __shfl_down(v, off, 64);
    if (lane == 0) reds[wave] = v;
  }
  __syncthreads();
  if (tid < N_EXP) logits[tid] = red[0][tid] + red[1][tid] + red[2][tid] + red[3][tid];
  __syncthreads();
  if (tid == 0) {
    float m = -1e30f;
    #pragma unroll
    for (int e = 0; e < N_EXP; e++) m = fmaxf(m, logits[e]);
    float p[N_EXP];
    #pragma unroll
    for (int e = 0; e < N_EXP; e++) p[e] = expf(logits[e] - m);
    int ids[TOPK]; float vs[TOPK]; float wsum = 0.f;
    #pragma unroll
    for (int k = 0; k < TOPK; k++) {
      int best = 0; float bv = -1.f;
      for (int e = 0; e < N_EXP; e++) {
        if (p[e] > bv) { bv = p[e]; best = e; }
      }
      ids[k] = best; vs[k] = bv; wsum += bv; p[best] = -2.f;
    }
    float inv = 1.f / wsum;
    float sgs = reds[0] + reds[1] + reds[2] + reds[3];
    sg[t] = 1.f / (1.f + expf(-sgs));
    #pragma unroll
    for (int k = 0; k < TOPK; k++) {
      int slot = t * TOPK + k;
      topw[slot] = vs[k] * inv;
      int pos = atomicAdd(&counts[ids[k]], 1);
      lists[ids[k] * T_TOK + pos] = slot;
    }
  }
}

// ---------------- x -> bf16 (halves all downstream A-request bytes) ----------------
__global__ __launch_bounds__(256) void xcvt_kernel(
    const float* __restrict__ x, bf16* __restrict__ xb)
{
  size_t i = ((size_t)blockIdx.x * 256 + threadIdx.x) * 8;
  f32x4 a = *(const f32x4*)(x + i);
  f32x4 b = *(const f32x4*)(x + i + 4);
  bf16x8 o;
  #pragma unroll
  for (int j = 0; j < 4; j++) { o[j] = (bf16)a[j]; o[4 + j] = (bf16)b[j]; }
  *(bf16x8*)(xb + i) = o;
}

// ------- fused gate/up dual GEMM + SwiGLU, 64x128 tile, BK=32, 512 threads -------
// A sourced from bf16 xb (8B/thread raw copy). Threads 0-255 stage Wg,
// 256-511 stage Wu. 2-deep register prefetch, swizzled LDS, one BAR per K-step.
__global__ __launch_bounds__(512) __attribute__((amdgpu_waves_per_eu(4, 4)))
void gateup_fused(
    const bf16* __restrict__ XB,
    const float* __restrict__ wg_, const float* __restrict__ wu_,
    const float* __restrict__ swg, const float* __restrict__ swu,
    bf16* __restrict__ act, bf16* __restrict__ acts,
    const int* __restrict__ lists, const int* __restrict__ counts,
    int n_shared, int sh_nfb, int actsN, int col_off)
{
  int id = blockIdx.x;
  bool gather = id >= n_shared;
  const float *Wg, *Wu; const int* lb = nullptr;
  int count, mt, fb, ldb, Nout; bf16* C;
  if (gather) {
    int g = id - n_shared;
    int j = g >> 3;
    int e = (g & 7) + 8 * (j / 96);   // expert e's 96 blocks share an XCD
    int rr = j % 96;
    mt = (rr / 6) * 64; fb = (rr % 6) * 128;
    count = counts[e]; lb = lists + e * T_TOK;
    Wg = wg_ + (size_t)e * H_DIM * F_DIM;
    Wu = wu_ + (size_t)e * H_DIM * F_DIM;
    ldb = F_DIM; Nout = F_DIM; C = act;
  } else {
    fb = (id % sh_nfb) * 128; mt = (id / sh_nfb) * 64;
    count = T_TOK; ldb = FS_DIM; Nout = actsN;
    Wg = swg + col_off; Wu = swu + col_off;
    C = acts;
  }
  if (mt >= count) return;

  __shared__ alignas(16) char sA [2][64 * 64];    // [64m][32k] bf16, swizzled
  __shared__ alignas(16) char sBg[2][128 * 64];   // [128n][32k] bf16, swizzled
  __shared__ alignas(16) char sBu[2][128 * 64];

  int tid = threadIdx.x;
  int lane = tid & 63, wid = tid >> 6;
  int wr = wid >> 2, wc = wid & 3;   // 2x4 waves, wave tile 32m x 32n
  int l15 = lane & 15, qB = (lane >> 4) << 4;

  const bf16* aptr;
  {
    int r = mt + (tid >> 3);
    int rc = r < count ? r : count - 1;
    int tok = gather ? (lb[rc] >> 2) : rc;
    aptr = XB + (size_t)tok * H_DIM + ((tid & 7) << 2);
  }
  int t8 = tid & 255;
  int bng = t8 & 31;             // n-quad 0..31
  int bk4 = (t8 >> 5) << 2;      // k base 0,4,..,28
  const float* bptr = (tid < 256 ? Wg : Wu) + (size_t)bk4 * ldb + fb + bng * 4;
  char* bds = (tid < 256) ? &sBg[0][0] : &sBu[0][0];

  f32x4 accg[2][2], accu[2][2];
  #pragma unroll
  for (int m = 0; m < 2; m++)
    #pragma unroll
    for (int n = 0; n < 2; n++) {
      accg[m][n] = (f32x4){0.f,0.f,0.f,0.f};
      accu[m][n] = (f32x4){0.f,0.f,0.f,0.f};
    }

  uint2 ava, avb; f32x4 bva[4], bvb[4];

  #define GU_ISSUE(av, bv, k0) do {                                   \
    av = *(const uint2*)(aptr + (k0));                                \
    _Pragma("unroll")                                                 \
    for (int r_ = 0; r_ < 4; r_++)                                    \
      bv[r_] = *(const f32x4*)(bptr + (size_t)((k0) + r_) * ldb);     \
    __builtin_amdgcn_sched_barrier(0);                                \
  } while (0)

  #define GU_STAGE(b, av, bv) do {                                    \
    *(uint2*)(sA[b] + swz(tid >> 3, (tid & 7) << 3)) = av;            \
    _Pragma("unroll")                                                 \
    for (int i_ = 0; i_ < 4; i_++) {                                  \
      bf16x4 tb;                                                      \
      tb[0]=(bf16)bv[0][i_]; tb[1]=(bf16)bv[1][i_];                   \
      tb[2]=(bf16)bv[2][i_]; tb[3]=(bf16)bv[3][i_];                   \
      *(bf16x4*)(bds + (b) * (128 * 64) + swz(bng * 4 + i_, bk4 << 1)) = tb; \
    } } while (0)

  #define GU_MFMA(b) do {                                             \
    __builtin_amdgcn_s_setprio(1);                                    \
    bf16x8 af0 = *(const bf16x8*)(sA[b] + swz(wr * 32 + l15, qB));    \
    bf16x8 af1 = *(const bf16x8*)(sA[b] + swz(wr * 32 + 16 + l15, qB)); \
    _Pragma("unroll")                                                 \
    for (int n_ = 0; n_ < 2; n_++) {                                  \
      int rb = wc * 32 + n_ * 16 + l15;                               \
      bf16x8 bg = *(const bf16x8*)(sBg[b] + swz(rb, qB));             \
      bf16x8 bu = *(const bf16x8*)(sBu[b] + swz(rb, qB));             \
      accg[0][n_] = __builtin_amdgcn_mfma_f32_16x16x32_bf16(af0, bg, accg[0][n_], 0,0,0); \
      accg[1][n_] = __builtin_amdgcn_mfma_f32_16x16x32_bf16(af1, bg, accg[1][n_], 0,0,0); \
      accu[0][n_] = __builtin_amdgcn_mfma_f32_16x16x32_bf16(af0, bu, accu[0][n_], 0,0,0); \
      accu[1][n_] = __builtin_amdgcn_mfma_f32_16x16x32_bf16(af1, bu, accu[1][n_], 0,0,0); \
    }                                                                 \
    __builtin_amdgcn_s_setprio(0);                                    \
  } while (0)

  const int NT = H_DIM / 32;   // 64
  GU_ISSUE(ava, bva, 0);
  GU_ISSUE(avb, bvb, 32);
  GU_STAGE(0, ava, bva);
  GU_ISSUE(ava, bva, 64);
  BAR();
  for (int t = 0; t < NT; t += 2) {
    GU_MFMA(0);                                    // tile t
    GU_STAGE(1, avb, bvb);                         // tile t+1
    if (t + 3 < NT) GU_ISSUE(avb, bvb, (t + 3) * 32);
    BAR();
    GU_MFMA(1);                                    // tile t+1
    if (t + 2 < NT) {
      GU_STAGE(0, ava, bva);                       // tile t+2
      if (t + 4 < NT) GU_ISSUE(ava, bva, (t + 4) * 32);
    }
    BAR();
  }
  #undef GU_ISSUE
  #undef GU_STAGE
  #undef GU_MFMA

  #pragma unroll
  for (int m = 0; m < 2; m++) {
    #pragma unroll
    for (int q = 0; q < 4; q++) {
      int gr = mt + wr * 32 + m * 16 + (lane >> 4) * 4 + q;
      if (gr < count) {
        size_t rowo = (gather ? (size_t)lb[gr] : (size_t)gr) * Nout;
        #pragma unroll
        for (int n = 0; n < 2; n++) {
          float g = accg[m][n][q], u = accu[m][n][q];
          C[rowo + fb + wc * 32 + n * 16 + l15] =
              (bf16)(g / (1.f + __expf(-g)) * u);
        }
      }
    }
  }
}

// ------- shared-expert down-proj, 64x128 tile, BK=32 (round-13 engine) -------
__global__ __launch_bounds__(256, 4) void dn_shared(
    const bf16* __restrict__ acts, const float* __restrict__ swd,
    float* __restrict__ out, const float* __restrict__ sg,
    int lda_sh, int kd_sh, int swd_off, int accum)
{
  int id = blockIdx.x;
  int nb = (id & 15) * 128, mt = (id >> 4) * 64;
  const bf16* A = acts; int lda = lda_sh, Kd = kd_sh;
  const float* W = swd + (size_t)swd_off * H_DIM;

  __shared__ alignas(16) char sA[2][64 * 64];
  __shared__ alignas(16) char sB[2][128 * 64];

  int tid = threadIdx.x;
  int lane = tid & 63, wid = tid >> 6;
  int wr = wid >> 1, wc = wid & 1;
  int l15 = lane & 15, qB = (lane >> 4) << 4;
  int bng = tid & 31;
  int bk4 = (tid >> 5) << 2;

  const bf16* aptr = A + (size_t)(mt + (tid >> 2)) * lda + ((tid & 3) << 3);
  const float* bptr = W + (size_t)bk4 * H_DIM + nb + bng * 4;

  f32x4 acc[2][4];
  #pragma unroll
  for (int m = 0; m < 2; m++)
    #pragma unroll
    for (int n = 0; n < 4; n++)
      acc[m][n] = (f32x4){0.f,0.f,0.f,0.f};

  uint4 ava, avb; f32x4 bva[4], bvb[4];

  #define DN_ISSUE(av, bv, k0) do {                                   \
    av = *(const uint4*)(aptr + (k0));                                \
    _Pragma("unroll")                                                 \
    for (int r_ = 0; r_ < 4; r_++)                                    \
      bv[r_] = *(const f32x4*)(bptr + (size_t)((k0) + r_) * H_DIM);   \
    } while (0)

  #define DN_STAGE(b, av, bv) do {                                    \
    *(uint4*)(sA[b] + swz(tid >> 2, (tid & 3) << 4)) = av;            \
    _Pragma("unroll")                                                 \
    for (int i_ = 0; i_ < 4; i_++) {                                  \
      bf16x4 tb;                                                      \
      tb[0]=(bf16)bv[0][i_]; tb[1]=(bf16)bv[1][i_];                   \
      tb[2]=(bf16)bv[2][i_]; tb[3]=(bf16)bv[3][i_];                   \
      *(bf16x4*)(sB[b] + swz(bng * 4 + i_, bk4 << 1)) = tb;           \
    } } while (0)

  #define DN_MFMA(b) do {                                             \
    __builtin_amdgcn_s_setprio(1);                                    \
    bf16x8 af0 = *(const bf16x8*)(sA[b] + swz(wr * 32 + l15, qB));    \
    bf16x8 af1 = *(const bf16x8*)(sA[b] + swz(wr * 32 + 16 + l15, qB)); \
    _Pragma("unroll")                                                 \
    for (int n_ = 0; n_ < 4; n_++) {                                  \
      bf16x8 bb = *(const bf16x8*)(sB[b] + swz(wc * 64 + n_ * 16 + l15, qB)); \
      acc[0][n_] = __builtin_amdgcn_mfma_f32_16x16x32_bf16(af0, bb, acc[0][n_], 0,0,0); \
      acc[1][n_] = __builtin_amdgcn_mfma_f32_16x16x32_bf16(af1, bb, acc[1][n_], 0,0,0); \
    }                                                                 \
    __builtin_amdgcn_s_setprio(0);                                    \
  } while (0)

  const int NT = Kd / 32;
  DN_ISSUE(ava, bva, 0);
  DN_ISSUE(avb, bvb, 32);
  DN_STAGE(0, ava, bva);
  DN_ISSUE(ava, bva, 64);
  BAR();
  for (int t = 0; t < NT; t += 2) {
    DN_MFMA(0);
    DN_STAGE(1, avb, bvb);
    if (t + 3 < NT) DN_ISSUE(avb, bvb, (t + 3) * 32);
    BAR();
    DN_MFMA(1);
    if (t + 2 < NT) {
      DN_STAGE(0, ava, bva);
      if (t + 4 < NT) DN_ISSUE(ava, bva, (t + 4) * 32);
    }
    BAR();
  }
  #undef DN_ISSUE
  #undef DN_STAGE
  #undef DN_MFMA

  #pragma unroll
  for (int m = 0; m < 2; m++) {
    #pragma unroll
    for (int q = 0; q < 4; q++) {
      int gr = mt + wr * 32 + m * 16 + (lane >> 4) * 4 + q;
      #pragma unroll
      for (int n = 0; n < 4; n++) {
        int col = nb + wc * 64 + n * 16 + l15;
        if (!accum) out[(size_t)gr * H_DIM + col] = sg[gr] * acc[m][n][q];
        else        out[(size_t)gr * H_DIM + col] += sg[gr] * acc[m][n][q];
      }
    }
  }
}

// ------- expert down-proj, full H, 64x128 tile (round-13 engine) -------
// writes dslot[slot][H_DIM] (bf16, unscaled). 128 blocks/expert, XCD-clustered.
__global__ __launch_bounds__(256, 4) void dn_expert(
    const bf16* __restrict__ act, const float* __restrict__ wd_,
    bf16* __restrict__ dslot,
    const int* __restrict__ lists, const int* __restrict__ counts)
{
  int g = blockIdx.x;
  int j = g >> 3;
  int e = (g & 7) + 8 * (j >> 7);   // expert e's 128 blocks share an XCD
  int rr = j & 127;
  int nb = (rr & 15) * 128;
  int mt = (rr >> 4) * 64;
  int count = counts[e];
  const int* lb = lists + e * T_TOK;
  if (mt >= count) return;
  const float* W = wd_ + (size_t)e * F_DIM * H_DIM;

  __shared__ alignas(16) char sA[2][64 * 64];
  __shared__ alignas(16) char sB[2][128 * 64];

  int tid = threadIdx.x;
  int lane = tid & 63, wid = tid >> 6;
  int wr = wid >> 1, wc = wid & 1;
  int l15 = lane & 15, qB = (lane >> 4) << 4;
  int bng = tid & 31;
  int bk4 = (tid >> 5) << 2;

  const bf16* aptr;
  {
    int r = mt + (tid >> 2);
    int rc = r < count ? r : count - 1;
    aptr = act + (size_t)lb[rc] * F_DIM + ((tid & 3) << 3);
  }
  const float* bptr = W + (size_t)bk4 * H_DIM + nb + bng * 4;

  f32x4 acc[2][4];
  #pragma unroll
  for (int m = 0; m < 2; m++)
    #pragma unroll
    for (int n = 0; n < 4; n++)
      acc[m][n] = (f32x4){0.f,0.f,0.f,0.f};

  uint4 ava, avb; f32x4 bva[4], bvb[4];

  #define DE_ISSUE(av, bv, k0) do {                                   \
    av = *(const uint4*)(aptr + (k0));                                \
    _Pragma("unroll")                                                 \
    for (int r_ = 0; r_ < 4; r_++)                                    \
      bv[r_] = *(const f32x4*)(bptr + (size_t)((k0) + r_) * H_DIM);   \
    } while (0)

  #define DE_STAGE(b, av, bv) do {                                    \
    *(uint4*)(sA[b] + swz(tid >> 2, (tid & 3) << 4)) = av;            \
    _Pragma("unroll")                                                 \
    for (int i_ = 0; i_ < 4; i_++) {                                  \
      bf16x4 tb;                                                      \
      tb[0]=(bf16)bv[0][i_]; tb[1]=(bf16)bv[1][i_];                   \
      tb[2]=(bf16)bv[2][i_]; tb[3]=(bf16)bv[3][i_];                   \
      *(bf16x4*)(sB[b] + swz(bng * 4 + i_, bk4 << 1)) = tb;           \
    } } while (0)

  #define DE_MFMA(b) do {                                             \
    __builtin_amdgcn_s_setprio(1);                                    \
    bf16x8 af0 = *(const bf16x8*)(sA[b] + swz(wr * 32 + l15, qB));    \
    bf16x8 af1 = *(const bf16x8*)(sA[b] + swz(wr * 32 + 16 + l15, qB)); \
    _Pragma("unroll")                                                 \
    for (int n_ = 0; n_ < 4; n_++) {                                  \
      bf16x8 bb = *(const bf16x8*)(sB[b] + swz(wc * 64 + n_ * 16 + l15, qB)); \
      acc[0][n_] = __builtin_amdgcn_mfma_f32_16x16x32_bf16(af0, bb, acc[0][n_], 0,0,0); \
      acc[1][n_] = __builtin_amdgcn_mfma_f32_16x16x32_bf16(af1, bb, acc[1][n_], 0,0,0); \
    }                                                                 \
    __builtin_amdgcn_s_setprio(0);                                    \
  } while (0)

  const int NT = F_DIM / 32;   // 24
  DE_ISSUE(ava, bva, 0);
  DE_ISSUE(avb, bvb, 32);
  DE_STAGE(0, ava, bva);
  DE_ISSUE(ava, bva, 64);
  BAR();
  for (int t = 0; t < NT; t += 2) {
    DE_MFMA(0);
    DE_STAGE(1, avb, bvb);
    if (t + 3 < NT) DE_ISSUE(avb, bvb, (t + 3) * 32);
    BAR();
    DE_MFMA(1);
    if (t + 2 < NT) {
      DE_STAGE(0, ava, bva);
      if (t + 4 < NT) DE_ISSUE(ava, bva, (t + 4) * 32);
    }
    BAR();
  }
  #undef DE_ISSUE
  #undef DE_STAGE
  #undef DE_MFMA

  #pragma unroll
  for (int m = 0; m < 2; m++) {
    #pragma unroll
    for (int q = 0; q < 4; q++) {
      int gr = mt + wr * 32 + m * 16 + (lane >> 4) * 4 + q;
      if (gr < count) {
        #pragma unroll
        for (int n = 0; n < 4; n++) {
          int col = nb + wc * 64 + n * 16 + l15;
          dslot[(size_t)lb[gr] * H_DIM + col] = (bf16)acc[m][n][q];
        }
      }
    }
  }
}

// ---------------- combine: out += sum_k topw*dslot ----------------
__global__ __launch_bounds__(256) void combine_kernel(
    const bf16* __restrict__ dslot, const float* __restrict__ topw,
    float* __restrict__ out)
{
  int t = blockIdx.x;
  int h = threadIdx.x * 8;
  float w0 = topw[t * 4 + 0], w1 = topw[t * 4 + 1];
  float w2 = topw[t * 4 + 2], w3 = topw[t * 4 + 3];
  bf16x8 a0 = *(const bf16x8*)&dslot[(size_t)(t * 4 + 0) * H_DIM + h];
  bf16x8 a1 = *(const bf16x8*)&dslot[(size_t)(t * 4 + 1) * H_DIM + h];
  bf16x8 a2 = *(const bf16x8*)&dslot[(size_t)(t * 4 + 2) * H_DIM + h];
  bf16x8 a3 = *(const bf16x8*)&dslot[(size_t)(t * 4 + 3) * H_DIM + h];
  f32x4 o0 = *(f32x4*)&out[(size_t)t * H_DIM + h];
  f32x4 o1 = *(f32x4*)&out[(size_t)t * H_DIM + h + 4];
  float o[8] = {o0[0], o0[1], o0[2], o0[3], o1[0], o1[1], o1[2], o1[3]};
  #pragma unroll
  for (int j = 0; j < 8; j++)
    o[j] += w0 * (float)a0[j] + w1 * (float)a1[j] + w2 * (float)a2[j]
          + w3 * (float)a3[j];
  *(f32x4*)&out[(size_t)t * H_DIM + h]     = (f32x4){o[0], o[1], o[2], o[3]};
  *(f32x4*)&out[(size_t)t * H_DIM + h + 4] = (f32x4){o[4], o[5], o[6], o[7]};
}

extern "C" void kernel_launch(void* const* d_in, const int* in_sizes, int n_in,
                              void* d_out, int out_size, void* d_ws, size_t ws_size,
                              hipStream_t stream) {
  const float* x   = (const float*)d_in[0];
  const float* rw  = (const float*)d_in[1];
  const float* wg  = (const float*)d_in[2];
  const float* wu  = (const float*)d_in[3];
  const float* wd  = (const float*)d_in[4];
  const float* swg = (const float*)d_in[5];
  const float* swu = (const float*)d_in[6];
  const float* swd = (const float*)d_in[7];
  const float* sgw = (const float*)d_in[8];
  float* out = (float*)d_out;
  char* ws = (char*)d_ws;

  // ws total ~23.2 MB. Aliasing: dslot (16.8 MB, full H) occupies the
  // xb+acts+tail region — xb and acts are dead before dn_expert runs.
  size_t off = 0;
  int*   counts = (int*)(ws + off); off += 256;
  int*   lists  = (int*)(ws + off); off += (size_t)N_EXP * T_TOK * 4;
  float* topw   = (float*)(ws + off); off += (size_t)T_TOK * TOPK * 4;
  float* sg     = (float*)(ws + off); off += (size_t)T_TOK * 4;
  bf16*  act    = (bf16*)(ws + off); off += (size_t)T_TOK * TOPK * F_DIM * 2;   // 6.3 MB
  size_t dslot_off = off;
  bf16*  xb     = (bf16*)(ws + off); off += (size_t)T_TOK * H_DIM * 2;          // 4.2 MB
  bf16*  acts   = (bf16*)(ws + off); off += (size_t)T_TOK * FS_HALF * 2;        // 4.2 MB
  off = dslot_off + (size_t)T_TOK * TOPK * H_DIM * 2;                           // 16.8 MB
  bf16*  dslot  = (bf16*)(ws + dslot_off);

  hipMemsetAsync(counts, 0, 256, stream);

  router_kernel<<<T_TOK, 256, 0, stream>>>(x, rw, sgw, topw, sg, counts, lists);
  xcvt_kernel<<<(T_TOK * H_DIM) / 2048, 256, 0, stream>>>(x, xb);

  const int SH_NFB = FS_HALF / 128;            // 16
  const int NSH_GU = SH_NFB * (T_TOK / 64);    // 256
  const int EXP_GU = N_EXP * 96;               // 3072

  // gate/up: experts + shared FS half 0
  gateup_fused<<<NSH_GU + EXP_GU, 512, 0, stream>>>(
      xb, wg, wu, swg, swu, act, acts, lists, counts,
      NSH_GU, SH_NFB, FS_HALF, 0);
  // shared down half 0 (out =)
  dn_shared<<<256, 256, 0, stream>>>(acts, swd, out, sg, FS_HALF, FS_HALF, 0, 0);
  // shared gate/up FS half 1 (reuses acts; xb still valid)
  gateup_fused<<<NSH_GU, 512, 0, stream>>>(
      xb, wg, wu, swg, swu, act, acts, lists, counts,
      NSH_GU, SH_NFB, FS_HALF, FS_HALF);
  // shared down half 1 (out +=) — last reader of acts/xb
  dn_shared<<<256, 256, 0, stream>>>(acts, swd, out, sg, FS_HALF, FS_HALF, FS_HALF, 1);

  // expert down (full H) into aliased dslot, then combine
  dn_expert<<<N_EXP * 128, 256, 0, stream>>>(act, wd, dslot, lists, counts);
  combine_kernel<<<T_TOK, 256, 0, stream>>>(dslot, topw, out);
}

// Round 19
// 410.962 us; speedup vs baseline: 1.0671x; 1.0430x over previous
//
#include <hip/hip_runtime.h>
#include <math.h>

#define T_TOK 1024
#define H_DIM 2048
#define N_EXP 32
#define TOPK  4
#define F_DIM 768
#define FS_DIM 4096
#define FS_HALF 2048

typedef __bf16 bf16;
typedef __attribute__((ext_vector_type(4))) __bf16 bf16x4;
typedef __attribute__((ext_vector_type(8))) __bf16 bf16x8;
typedef __attribute__((ext_vector_type(4))) float f32x4;

// raw barrier: drain ds ops (lgkm) but let global prefetch loads stay in
// flight across the barrier; sched_barrier(0) pins code motion at the BAR.
#define BAR() do {                                        \
    asm volatile("s_waitcnt lgkmcnt(0)" ::: "memory");    \
    __builtin_amdgcn_s_barrier();                         \
    __builtin_amdgcn_sched_barrier(0);                    \
  } while (0)

// XOR-swizzled LDS offset: rows are 32 bf16 = 64B.
__device__ __forceinline__ int swz(int row, int colB) {
  return row * 64 + (colB ^ (((row >> 2) & 3) << 4));
}

// ---------------- router: fp32 logits -> softmax -> top4 -> lists ----------------
__global__ __launch_bounds__(256) void router_kernel(
    const float* __restrict__ x, const float* __restrict__ rw,
    const float* __restrict__ sgw,
    float* __restrict__ topw, float* __restrict__ sg,
    int* __restrict__ counts, int* __restrict__ lists)
{
  int t = blockIdx.x; int tid = threadIdx.x;
  int lane = tid & 63, wave = tid >> 6;
  float acc[N_EXP];
  #pragma unroll
  for (int e = 0; e < N_EXP; e++) acc[e] = 0.f;
  float accs = 0.f;
  const float* xr = x + (size_t)t * H_DIM;
  for (int h = tid; h < H_DIM; h += 256) {
    float xv = xr[h];
    accs += xv * sgw[h];
    #pragma unroll
    for (int e = 0; e < N_EXP; e++) acc[e] += xv * rw[e * H_DIM + h];
  }
  __shared__ float red[4][N_EXP];
  __shared__ float reds[4];
  __shared__ float logits[N_EXP];
  #pragma unroll
  for (int e = 0; e < N_EXP; e++) {
    float v = acc[e];
    for (int off = 32; off; off >>= 1) v += __shfl_down(v, off, 64);
    if (lane == 0) red[wave][e] = v;
  }
  {
    float v = accs;
    for (int off = 32; off; off >>= 1) v += __shfl_down(v, off, 64);
    if (lane == 0) reds[wave] = v;
  }
  __syncthreads();
  if (tid < N_EXP) logits[tid] = red[0][tid] + red[1][tid] + red[2][tid] + red[3][tid];
  __syncthreads();
  if (tid == 0) {
    float m = -1e30f;
    #pragma unroll
    for (int e = 0; e < N_EXP; e++) m = fmaxf(m, logits[e]);
    float p[N_EXP];
    #pragma unroll
    for (int e = 0; e < N_EXP; e++) p[e] = expf(logits[e] - m);
    int ids[TOPK]; float vs[TOPK]; float wsum = 0.f;
    #pragma unroll
    for (int k = 0; k < TOPK; k++) {
      int best = 0; float bv = -1.f;
      for (int e = 0; e < N_EXP; e++) {
        if (p[e] > bv) { bv = p[e]; best = e; }
      }
      ids[k] = best; vs[k] = bv; wsum += bv; p[best] = -2.f;
    }
    float inv = 1.f / wsum;
    float sgs = reds[0] + reds[1] + reds[2] + reds[3];
    sg[t] = 1.f / (1.f + expf(-sgs));
    #pragma unroll
    for (int k = 0; k < TOPK; k++) {
      int slot = t * TOPK + k;
      topw[slot] = vs[k] * inv;
      int pos = atomicAdd(&counts[ids[k]], 1);
      lists[ids[k] * T_TOK + pos] = slot;
    }
  }
}

// ---------------- x -> bf16 (halves big-gateup A-request bytes) ----------------
__global__ __launch_bounds__(256) void xcvt_kernel(
    const float* __restrict__ x, bf16* __restrict__ xb)
{
  size_t i = ((size_t)blockIdx.x * 256 + threadIdx.x) * 8;
  f32x4 a = *(const f32x4*)(x + i);
  f32x4 b = *(const f32x4*)(x + i + 4);
  bf16x8 o;
  #pragma unroll
  for (int j = 0; j < 4; j++) { o[j] = (bf16)a[j]; o[4 + j] = (bf16)b[j]; }
  *(bf16x8*)(xb + i) = o;
}

// ------- big gate/up dual GEMM + SwiGLU, bf16 A, 64x128 tile, BK=32, 512 thr ------
// (r18's measured-203µs kernel, verbatim)
__global__ __launch_bounds__(512) __attribute__((amdgpu_waves_per_eu(4, 4)))
void gateup_xb(
    const bf16* __restrict__ XB,
    const float* __restrict__ wg_, const float* __restrict__ wu_,
    const float* __restrict__ swg, const float* __restrict__ swu,
    bf16* __restrict__ act, bf16* __restrict__ acts,
    const int* __restrict__ lists, const int* __restrict__ counts,
    int n_shared, int sh_nfb, int actsN, int col_off)
{
  int id = blockIdx.x;
  bool gather = id >= n_shared;
  const float *Wg, *Wu; const int* lb = nullptr;
  int count, mt, fb, ldb, Nout; bf16* C;
  if (gather) {
    int g = id - n_shared;
    int j = g >> 3;
    int e = (g & 7) + 8 * (j / 96);   // expert e's 96 blocks share an XCD
    int rr = j % 96;
    mt = (rr / 6) * 64; fb = (rr % 6) * 128;
    count = counts[e]; lb = lists + e * T_TOK;
    Wg = wg_ + (size_t)e * H_DIM * F_DIM;
    Wu = wu_ + (size_t)e * H_DIM * F_DIM;
    ldb = F_DIM; Nout = F_DIM; C = act;
  } else {
    fb = (id % sh_nfb) * 128; mt = (id / sh_nfb) * 64;
    count = T_TOK; ldb = FS_DIM; Nout = actsN;
    Wg = swg + col_off; Wu = swu + col_off;
    C = acts;
  }
  if (mt >= count) return;

  __shared__ alignas(16) char sA [2][64 * 64];
  __shared__ alignas(16) char sBg[2][128 * 64];
  __shared__ alignas(16) char sBu[2][128 * 64];

  int tid = threadIdx.x;
  int lane = tid & 63, wid = tid >> 6;
  int wr = wid >> 2, wc = wid & 3;   // 2x4 waves, wave tile 32m x 32n
  int l15 = lane & 15, qB = (lane >> 4) << 4;

  const bf16* aptr;
  {
    int r = mt + (tid >> 3);
    int rc = r < count ? r : count - 1;
    int tok = gather ? (lb[rc] >> 2) : rc;
    aptr = XB + (size_t)tok * H_DIM + ((tid & 7) << 2);
  }
  int t8 = tid & 255;
  int bng = t8 & 31;
  int bk4 = (t8 >> 5) << 2;
  const float* bptr = (tid < 256 ? Wg : Wu) + (size_t)bk4 * ldb + fb + bng * 4;
  char* bds = (tid < 256) ? &sBg[0][0] : &sBu[0][0];

  f32x4 accg[2][2], accu[2][2];
  #pragma unroll
  for (int m = 0; m < 2; m++)
    #pragma unroll
    for (int n = 0; n < 2; n++) {
      accg[m][n] = (f32x4){0.f,0.f,0.f,0.f};
      accu[m][n] = (f32x4){0.f,0.f,0.f,0.f};
    }

  uint2 ava, avb; f32x4 bva[4], bvb[4];

  #define GU_ISSUE(av, bv, k0) do {                                   \
    av = *(const uint2*)(aptr + (k0));                                \
    _Pragma("unroll")                                                 \
    for (int r_ = 0; r_ < 4; r_++)                                    \
      bv[r_] = *(const f32x4*)(bptr + (size_t)((k0) + r_) * ldb);     \
    __builtin_amdgcn_sched_barrier(0);                                \
  } while (0)

  #define GU_STAGE(b, av, bv) do {                                    \
    *(uint2*)(sA[b] + swz(tid >> 3, (tid & 7) << 3)) = av;            \
    _Pragma("unroll")                                                 \
    for (int i_ = 0; i_ < 4; i_++) {                                  \
      bf16x4 tb;                                                      \
      tb[0]=(bf16)bv[0][i_]; tb[1]=(bf16)bv[1][i_];                   \
      tb[2]=(bf16)bv[2][i_]; tb[3]=(bf16)bv[3][i_];                   \
      *(bf16x4*)(bds + (b) * (128 * 64) + swz(bng * 4 + i_, bk4 << 1)) = tb; \
    } } while (0)

  #define GU_MFMA(b) do {                                             \
    __builtin_amdgcn_s_setprio(1);                                    \
    bf16x8 af0 = *(const bf16x8*)(sA[b] + swz(wr * 32 + l15, qB));    \
    bf16x8 af1 = *(const bf16x8*)(sA[b] + swz(wr * 32 + 16 + l15, qB)); \
    _Pragma("unroll")                                                 \
    for (int n_ = 0; n_ < 2; n_++) {                                  \
      int rb = wc * 32 + n_ * 16 + l15;                               \
      bf16x8 bg = *(const bf16x8*)(sBg[b] + swz(rb, qB));             \
      bf16x8 bu = *(const bf16x8*)(sBu[b] + swz(rb, qB));             \
      accg[0][n_] = __builtin_amdgcn_mfma_f32_16x16x32_bf16(af0, bg, accg[0][n_], 0,0,0); \
      accg[1][n_] = __builtin_amdgcn_mfma_f32_16x16x32_bf16(af1, bg, accg[1][n_], 0,0,0); \
      accu[0][n_] = __builtin_amdgcn_mfma_f32_16x16x32_bf16(af0, bu, accu[0][n_], 0,0,0); \
      accu[1][n_] = __builtin_amdgcn_mfma_f32_16x16x32_bf16(af1, bu, accu[1][n_], 0,0,0); \
    }                                                                 \
    __builtin_amdgcn_s_setprio(0);                                    \
  } while (0)

  const int NT = H_DIM / 32;   // 64
  GU_ISSUE(ava, bva, 0);
  GU_ISSUE(avb, bvb, 32);
  GU_STAGE(0, ava, bva);
  GU_ISSUE(ava, bva, 64);
  BAR();
  for (int t = 0; t < NT; t += 2) {
    GU_MFMA(0);
    GU_STAGE(1, avb, bvb);
    if (t + 3 < NT) GU_ISSUE(avb, bvb, (t + 3) * 32);
    BAR();
    GU_MFMA(1);
    if (t + 2 < NT) {
      GU_STAGE(0, ava, bva);
      if (t + 4 < NT) GU_ISSUE(ava, bva, (t + 4) * 32);
    }
    BAR();
  }
  #undef GU_ISSUE
  #undef GU_STAGE
  #undef GU_MFMA

  #pragma unroll
  for (int m = 0; m < 2; m++) {
    #pragma unroll
    for (int q = 0; q < 4; q++) {
      int gr = mt + wr * 32 + m * 16 + (lane >> 4) * 4 + q;
      if (gr < count) {
        size_t rowo = (gather ? (size_t)lb[gr] : (size_t)gr) * Nout;
        #pragma unroll
        for (int n = 0; n < 2; n++) {
          float g = accg[m][n][q], u = accu[m][n][q];
          C[rowo + fb + wc * 32 + n * 16 + l15] =
              (bf16)(g / (1.f + __expf(-g)) * u);
        }
      }
    }
  }
}

// ------- shared-only gate/up pass, fp32 A (r13 kernel), for FS half 1 -------
__global__ __launch_bounds__(512) __attribute__((amdgpu_waves_per_eu(4, 4)))
void gateup_f32(
    const float* __restrict__ X,
    const float* __restrict__ swg, const float* __restrict__ swu,
    bf16* __restrict__ acts, int sh_nfb, int actsN, int col_off)
{
  int id = blockIdx.x;
  int fb = (id % sh_nfb) * 128, mt = (id / sh_nfb) * 64;
  const float* Wg = swg + col_off;
  const float* Wu = swu + col_off;
  const int ldb = FS_DIM;

  __shared__ alignas(16) char sA [2][64 * 64];
  __shared__ alignas(16) char sBg[2][128 * 64];
  __shared__ alignas(16) char sBu[2][128 * 64];

  int tid = threadIdx.x;
  int lane = tid & 63, wid = tid >> 6;
  int wr = wid >> 2, wc = wid & 3;
  int l15 = lane & 15, qB = (lane >> 4) << 4;

  const float* aptr = X + (size_t)(mt + (tid >> 3)) * H_DIM + ((tid & 7) << 2);
  int t8 = tid & 255;
  int bng = t8 & 31;
  int bk4 = (t8 >> 5) << 2;
  const float* bptr = (tid < 256 ? Wg : Wu) + (size_t)bk4 * ldb + fb + bng * 4;
  char* bds = (tid < 256) ? &sBg[0][0] : &sBu[0][0];

  f32x4 accg[2][2], accu[2][2];
  #pragma unroll
  for (int m = 0; m < 2; m++)
    #pragma unroll
    for (int n = 0; n < 2; n++) {
      accg[m][n] = (f32x4){0.f,0.f,0.f,0.f};
      accu[m][n] = (f32x4){0.f,0.f,0.f,0.f};
    }

  f32x4 ava, bva[4], avb, bvb[4];

  #define GF_ISSUE(av, bv, k0) do {                                   \
    av = *(const f32x4*)(aptr + (k0));                                \
    _Pragma("unroll")                                                 \
    for (int r_ = 0; r_ < 4; r_++)                                    \
      bv[r_] = *(const f32x4*)(bptr + (size_t)((k0) + r_) * ldb);     \
    __builtin_amdgcn_sched_barrier(0);                                \
  } while (0)

  #define GF_STAGE(b, av, bv) do {                                    \
    bf16x4 ta;                                                        \
    ta[0]=(bf16)av[0]; ta[1]=(bf16)av[1];                             \
    ta[2]=(bf16)av[2]; ta[3]=(bf16)av[3];                             \
    *(bf16x4*)(sA[b] + swz(tid >> 3, (tid & 7) << 3)) = ta;           \
    _Pragma("unroll")                                                 \
    for (int i_ = 0; i_ < 4; i_++) {                                  \
      bf16x4 tb;                                                      \
      tb[0]=(bf16)bv[0][i_]; tb[1]=(bf16)bv[1][i_];                   \
      tb[2]=(bf16)bv[2][i_]; tb[3]=(bf16)bv[3][i_];                   \
      *(bf16x4*)(bds + (b) * (128 * 64) + swz(bng * 4 + i_, bk4 << 1)) = tb; \
    } } while (0)

  #define GF_MFMA(b) do {                                             \
    __builtin_amdgcn_s_setprio(1);                                    \
    bf16x8 af0 = *(const bf16x8*)(sA[b] + swz(wr * 32 + l15, qB));    \
    bf16x8 af1 = *(const bf16x8*)(sA[b] + swz(wr * 32 + 16 + l15, qB)); \
    _Pragma("unroll")                                                 \
    for (int n_ = 0; n_ < 2; n_++) {                                  \
      int rb = wc * 32 + n_ * 16 + l15;                               \
      bf16x8 bg = *(const bf16x8*)(sBg[b] + swz(rb, qB));             \
      bf16x8 bu = *(const bf16x8*)(sBu[b] + swz(rb, qB));             \
      accg[0][n_] = __builtin_amdgcn_mfma_f32_16x16x32_bf16(af0, bg, accg[0][n_], 0,0,0); \
      accg[1][n_] = __builtin_amdgcn_mfma_f32_16x16x32_bf16(af1, bg, accg[1][n_], 0,0,0); \
      accu[0][n_] = __builtin_amdgcn_mfma_f32_16x16x32_bf16(af0, bu, accu[0][n_], 0,0,0); \
      accu[1][n_] = __builtin_amdgcn_mfma_f32_16x16x32_bf16(af1, bu, accu[1][n_], 0,0,0); \
    }                                                                 \
    __builtin_amdgcn_s_setprio(0);                                    \
  } while (0)

  const int NT = H_DIM / 32;   // 64
  GF_ISSUE(ava, bva, 0);
  GF_ISSUE(avb, bvb, 32);
  GF_STAGE(0, ava, bva);
  GF_ISSUE(ava, bva, 64);
  BAR();
  for (int t = 0; t < NT; t += 2) {
    GF_MFMA(0);
    GF_STAGE(1, avb, bvb);
    if (t + 3 < NT) GF_ISSUE(avb, bvb, (t + 3) * 32);
    BAR();
    GF_MFMA(1);
    if (t + 2 < NT) {
      GF_STAGE(0, ava, bva);
      if (t + 4 < NT) GF_ISSUE(ava, bva, (t + 4) * 32);
    }
    BAR();
  }
  #undef GF_ISSUE
  #undef GF_STAGE
  #undef GF_MFMA

  #pragma unroll
  for (int m = 0; m < 2; m++) {
    #pragma unroll
    for (int q = 0; q < 4; q++) {
      int gr = mt + wr * 32 + m * 16 + (lane >> 4) * 4 + q;
      size_t rowo = (size_t)gr * actsN;
      #pragma unroll
      for (int n = 0; n < 2; n++) {
        float g = accg[m][n][q], u = accu[m][n][q];
        acts[rowo + fb + wc * 32 + n * 16 + l15] =
            (bf16)(g / (1.f + __expf(-g)) * u);
      }
    }
  }
}

// ------- fused down-proj (r13 kernel): experts + shared in one dispatch -------
__global__ __launch_bounds__(256, 4) void down_fused(
    const bf16* __restrict__ act, const bf16* __restrict__ acts,
    const float* __restrict__ wd_, const float* __restrict__ swd,
    bf16* __restrict__ dslot, float* __restrict__ out,
    const float* __restrict__ sg,
    const int* __restrict__ lists, const int* __restrict__ counts,
    int n_shared, int lda_sh, int kd_sh, int swd_off, int accum)
{
  int id = blockIdx.x;
  bool expert = id >= n_shared;
  const bf16* A; const float* W; const int* lb = nullptr;
  int count, mt, nb, Kd, lda;
  if (expert) {
    int g = id - n_shared;
    int j = g >> 3;
    int e = (g & 7) + 8 * (j >> 7);   // expert e's 128 blocks share an XCD
    int rr = j & 127;
    nb = (rr & 15) * 128; mt = (rr >> 4) * 64;
    count = counts[e]; lb = lists + e * T_TOK;
    A = act; lda = F_DIM; Kd = F_DIM;
    W = wd_ + (size_t)e * F_DIM * H_DIM;
  } else {
    nb = (id & 15) * 128; mt = (id >> 4) * 64;
    count = T_TOK; A = acts; lda = lda_sh; Kd = kd_sh;
    W = swd + (size_t)swd_off * H_DIM;
  }
  if (mt >= count) return;

  __shared__ alignas(16) char sA[2][64 * 64];
  __shared__ alignas(16) char sB[2][128 * 64];

  int tid = threadIdx.x;
  int lane = tid & 63, wid = tid >> 6;
  int wr = wid >> 1, wc = wid & 1;
  int l15 = lane & 15, qB = (lane >> 4) << 4;
  int bng = tid & 31;
  int bk4 = (tid >> 5) << 2;

  const bf16* aptr;
  {
    int r = mt + (tid >> 2);
    int rc = r < count ? r : count - 1;
    int ar = expert ? lb[rc] : rc;
    aptr = A + (size_t)ar * lda + ((tid & 3) << 3);
  }
  const float* bptr = W + (size_t)bk4 * H_DIM + nb + bng * 4;

  f32x4 acc[2][4];
  #pragma unroll
  for (int m = 0; m < 2; m++)
    #pragma unroll
    for (int n = 0; n < 4; n++)
      acc[m][n] = (f32x4){0.f,0.f,0.f,0.f};

  uint4 ava, avb; f32x4 bva[4], bvb[4];

  #define DN_ISSUE(av, bv, k0) do {                                   \
    av = *(const uint4*)(aptr + (k0));                                \
    _Pragma("unroll")                                                 \
    for (int r_ = 0; r_ < 4; r_++)                                    \
      bv[r_] = *(const f32x4*)(bptr + (size_t)((k0) + r_) * H_DIM);   \
    } while (0)

  #define DN_STAGE(b, av, bv) do {                                    \
    *(uint4*)(sA[b] + swz(tid >> 2, (tid & 3) << 4)) = av;            \
    _Pragma("unroll")                                                 \
    for (int i_ = 0; i_ < 4; i_++) {                                  \
      bf16x4 tb;                                                      \
      tb[0]=(bf16)bv[0][i_]; tb[1]=(bf16)bv[1][i_];                   \
      tb[2]=(bf16)bv[2][i_]; tb[3]=(bf16)bv[3][i_];                   \
      *(bf16x4*)(sB[b] + swz(bng * 4 + i_, bk4 << 1)) = tb;           \
    } } while (0)

  #define DN_MFMA(b) do {                                             \
    __builtin_amdgcn_s_setprio(1);                                    \
    bf16x8 af0 = *(const bf16x8*)(sA[b] + swz(wr * 32 + l15, qB));    \
    bf16x8 af1 = *(const bf16x8*)(sA[b] + swz(wr * 32 + 16 + l15, qB)); \
    _Pragma("unroll")                                                 \
    for (int n_ = 0; n_ < 4; n_++) {                                  \
      bf16x8 bb = *(const bf16x8*)(sB[b] + swz(wc * 64 + n_ * 16 + l15, qB)); \
      acc[0][n_] = __builtin_amdgcn_mfma_f32_16x16x32_bf16(af0, bb, acc[0][n_], 0,0,0); \
      acc[1][n_] = __builtin_amdgcn_mfma_f32_16x16x32_bf16(af1, bb, acc[1][n_], 0,0,0); \
    }                                                                 \
    __builtin_amdgcn_s_setprio(0);                                    \
  } while (0)

  const int NT = Kd / 32;   // 24 or 64 (even)
  DN_ISSUE(ava, bva, 0);
  DN_ISSUE(avb, bvb, 32);
  DN_STAGE(0, ava, bva);
  DN_ISSUE(ava, bva, 64);
  BAR();
  for (int t = 0; t < NT; t += 2) {
    DN_MFMA(0);
    DN_STAGE(1, avb, bvb);
    if (t + 3 < NT) DN_ISSUE(avb, bvb, (t + 3) * 32);
    BAR();
    DN_MFMA(1);
    if (t + 2 < NT) {
      DN_STAGE(0, ava, bva);
      if (t + 4 < NT) DN_ISSUE(ava, bva, (t + 4) * 32);
    }
    BAR();
  }
  #undef DN_ISSUE
  #undef DN_STAGE
  #undef DN_MFMA

  #pragma unroll
  for (int m = 0; m < 2; m++) {
    #pragma unroll
    for (int q = 0; q < 4; q++) {
      int gr = mt + wr * 32 + m * 16 + (lane >> 4) * 4 + q;
      if (gr < count) {
        #pragma unroll
        for (int n = 0; n < 4; n++) {
          int col = nb + wc * 64 + n * 16 + l15;
          if (expert) {
            dslot[(size_t)lb[gr] * H_DIM + col] = (bf16)acc[m][n][q];
          } else if (!accum) {
            out[(size_t)gr * H_DIM + col] = sg[gr] * acc[m][n][q];
          } else {
            out[(size_t)gr * H_DIM + col] += sg[gr] * acc[m][n][q];
          }
        }
      }
    }
  }
}

// ---------------- combine: out += sum_k topw*dslot ----------------
__global__ __launch_bounds__(256) void combine_kernel(
    const bf16* __restrict__ dslot, const float* __restrict__ topw,
    float* __restrict__ out)
{
  int t = blockIdx.x;
  int h = threadIdx.x * 8;
  float w0 = topw[t * 4 + 0], w1 = topw[t * 4 + 1];
  float w2 = topw[t * 4 + 2], w3 = topw[t * 4 + 3];
  bf16x8 a0 = *(const bf16x8*)&dslot[(size_t)(t * 4 + 0) * H_DIM + h];
  bf16x8 a1 = *(const bf16x8*)&dslot[(size_t)(t * 4 + 1) * H_DIM + h];
  bf16x8 a2 = *(const bf16x8*)&dslot[(size_t)(t * 4 + 2) * H_DIM + h];
  bf16x8 a3 = *(const bf16x8*)&dslot[(size_t)(t * 4 + 3) * H_DIM + h];
  f32x4 o0 = *(f32x4*)&out[(size_t)t * H_DIM + h];
  f32x4 o1 = *(f32x4*)&out[(size_t)t * H_DIM + h + 4];
  float o[8] = {o0[0], o0[1], o0[2], o0[3], o1[0], o1[1], o1[2], o1[3]};
  #pragma unroll
  for (int j = 0; j < 8; j++)
    o[j] += w0 * (float)a0[j] + w1 * (float)a1[j] + w2 * (float)a2[j]
          + w3 * (float)a3[j];
  *(f32x4*)&out[(size_t)t * H_DIM + h]     = (f32x4){o[0], o[1], o[2], o[3]};
  *(f32x4*)&out[(size_t)t * H_DIM + h + 4] = (f32x4){o[4], o[5], o[6], o[7]};
}

extern "C" void kernel_launch(void* const* d_in, const int* in_sizes, int n_in,
                              void* d_out, int out_size, void* d_ws, size_t ws_size,
                              hipStream_t stream) {
  const float* x   = (const float*)d_in[0];
  const float* rw  = (const float*)d_in[1];
  const float* wg  = (const float*)d_in[2];
  const float* wu  = (const float*)d_in[3];
  const float* wd  = (const float*)d_in[4];
  const float* swg = (const float*)d_in[5];
  const float* swu = (const float*)d_in[6];
  const float* swd = (const float*)d_in[7];
  const float* sgw = (const float*)d_in[8];
  float* out = (float*)d_out;
  char* ws = (char*)d_ws;

  // ws total 27.45 MB (r13's proven-safe layout). xb aliases the first
  // 4.2 MB of dslot: xb is dead before down_fused writes dslot.
  size_t off = 0;
  int*   counts = (int*)(ws + off); off += 256;
  int*   lists  = (int*)(ws + off); off += (size_t)N_EXP * T_TOK * 4;
  float* topw   = (float*)(ws + off); off += (size_t)T_TOK * TOPK * 4;
  float* sg     = (float*)(ws + off); off += (size_t)T_TOK * 4;
  bf16*  act    = (bf16*)(ws + off); off += (size_t)T_TOK * TOPK * F_DIM * 2;   // 6.3 MB
  bf16*  acts   = (bf16*)(ws + off); off += (size_t)T_TOK * FS_HALF * 2;        // 4.2 MB
  bf16*  dslot  = (bf16*)(ws + off); off += (size_t)T_TOK * TOPK * H_DIM * 2;   // 16.8 MB
  bf16*  xb     = dslot;   // alias: first 4.2 MB of dslot

  hipMemsetAsync(counts, 0, 256, stream);

  router_kernel<<<T_TOK, 256, 0, stream>>>(x, rw, sgw, topw, sg, counts, lists);
  xcvt_kernel<<<(T_TOK * H_DIM) / 2048, 256, 0, stream>>>(x, xb);

  const int SH_NFB = FS_HALF / 128;            // 16
  const int NSH_GU = SH_NFB * (T_TOK / 64);    // 256
  const int EXP_GU = N_EXP * 96;               // 3072
  const int DN_EXP = N_EXP * 128;              // 4096

  // 1. big gate/up (bf16 A): experts -> act, shared FS half0 -> acts
  gateup_xb<<<NSH_GU + EXP_GU, 512, 0, stream>>>(
      xb, wg, wu, swg, swu, act, acts, lists, counts,
      NSH_GU, SH_NFB, FS_HALF, 0);
  // 2. big down: experts -> dslot (clobbers xb, now dead), shared h0 -> out
  down_fused<<<256 + DN_EXP, 256, 0, stream>>>(
      act, acts, wd, swd, dslot, out, sg, lists, counts,
      256, FS_HALF, FS_HALF, 0, 0);
  // 3. shared gate/up FS half1 (fp32 A; x is L2/L3-resident)
  gateup_f32<<<NSH_GU, 512, 0, stream>>>(
      x, swg, swu, acts, SH_NFB, FS_HALF, FS_HALF);
  // 4. shared down half1 (out +=)
  down_fused<<<256, 256, 0, stream>>>(
      act, acts, wd, swd, dslot, out, sg, lists, counts,
      256, FS_HALF, FS_HALF, FS_HALF, 1);
  // 5. combine expert contributions
  combine_kernel<<<T_TOK, 256, 0, stream>>>(dslot, topw, out);
}

// Round 20
// 410.075 us; speedup vs baseline: 1.0694x; 1.0022x over previous
//
#include <hip/hip_runtime.h>
#include <math.h>

#define T_TOK 1024
#define H_DIM 2048
#define N_EXP 32
#define TOPK  4
#define F_DIM 768
#define FS_DIM 4096
#define FS_HALF 2048

typedef __bf16 bf16;
typedef __attribute__((ext_vector_type(4))) __bf16 bf16x4;
typedef __attribute__((ext_vector_type(8))) __bf16 bf16x8;
typedef __attribute__((ext_vector_type(4))) float f32x4;

// raw barrier: drain ds ops (lgkm) but let global prefetch loads stay in
// flight across the barrier; sched_barrier(0) pins code motion at the BAR.
#define BAR() do {                                        \
    asm volatile("s_waitcnt lgkmcnt(0)" ::: "memory");    \
    __builtin_amdgcn_s_barrier();                         \
    __builtin_amdgcn_sched_barrier(0);                    \
  } while (0)

// XOR-swizzled LDS offset: rows are 32 bf16 = 64B.
__device__ __forceinline__ int swz(int row, int colB) {
  return row * 64 + (colB ^ (((row >> 2) & 3) << 4));
}

// ---------------- router: fp32 logits -> softmax -> top4 -> lists ----------------
__global__ __launch_bounds__(256) void router_kernel(
    const float* __restrict__ x, const float* __restrict__ rw,
    const float* __restrict__ sgw,
    float* __restrict__ topw, float* __restrict__ sg,
    int* __restrict__ counts, int* __restrict__ lists)
{
  int t = blockIdx.x; int tid = threadIdx.x;
  int lane = tid & 63, wave = tid >> 6;
  float acc[N_EXP];
  #pragma unroll
  for (int e = 0; e < N_EXP; e++) acc[e] = 0.f;
  float accs = 0.f;
  const float* xr = x + (size_t)t * H_DIM;
  for (int h = tid; h < H_DIM; h += 256) {
    float xv = xr[h];
    accs += xv * sgw[h];
    #pragma unroll
    for (int e = 0; e < N_EXP; e++) acc[e] += xv * rw[e * H_DIM + h];
  }
  __shared__ float red[4][N_EXP];
  __shared__ float reds[4];
  __shared__ float logits[N_EXP];
  #pragma unroll
  for (int e = 0; e < N_EXP; e++) {
    float v = acc[e];
    for (int off = 32; off; off >>= 1) v += __shfl_down(v, off, 64);
    if (lane == 0) red[wave][e] = v;
  }
  {
    float v = accs;
    for (int off = 32; off; off >>= 1) v += __shfl_down(v, off, 64);
    if (lane == 0) reds[wave] = v;
  }
  __syncthreads();
  if (tid < N_EXP) logits[tid] = red[0][tid] + red[1][tid] + red[2][tid] + red[3][tid];
  __syncthreads();
  if (tid == 0) {
    float m = -1e30f;
    #pragma unroll
    for (int e = 0; e < N_EXP; e++) m = fmaxf(m, logits[e]);
    float p[N_EXP];
    #pragma unroll
    for (int e = 0; e < N_EXP; e++) p[e] = expf(logits[e] - m);
    int ids[TOPK]; float vs[TOPK]; float wsum = 0.f;
    #pragma unroll
    for (int k = 0; k < TOPK; k++) {
      int best = 0; float bv = -1.f;
      for (int e = 0; e < N_EXP; e++) {
        if (p[e] > bv) { bv = p[e]; best = e; }
      }
      ids[k] = best; vs[k] = bv; wsum += bv; p[best] = -2.f;
    }
    float inv = 1.f / wsum;
    float sgs = reds[0] + reds[1] + reds[2] + reds[3];
    sg[t] = 1.f / (1.f + expf(-sgs));
    #pragma unroll
    for (int k = 0; k < TOPK; k++) {
      int slot = t * TOPK + k;
      topw[slot] = vs[k] * inv;
      int pos = atomicAdd(&counts[ids[k]], 1);
      lists[ids[k] * T_TOK + pos] = slot;
    }
  }
}

// ---------------- x -> bf16 (halves big-gateup A-request bytes) ----------------
__global__ __launch_bounds__(256) void xcvt_kernel(
    const float* __restrict__ x, bf16* __restrict__ xb)
{
  size_t i = ((size_t)blockIdx.x * 256 + threadIdx.x) * 8;
  f32x4 a = *(const f32x4*)(x + i);
  f32x4 b = *(const f32x4*)(x + i + 4);
  bf16x8 o;
  #pragma unroll
  for (int j = 0; j < 4; j++) { o[j] = (bf16)a[j]; o[4 + j] = (bf16)b[j]; }
  *(bf16x8*)(xb + i) = o;
}

// ------- big gate/up dual GEMM + SwiGLU, bf16 A, 64x128 tile, BK=32, 512 thr ------
// Experts (3072 blocks) + shared expert FULL FS (512 blocks): shared fb<16 ->
// acts0, fb>=16 -> acts1 (aliased into dslot[4.2:8.4MB]; dead before dn_expert).
__global__ __launch_bounds__(512) __attribute__((amdgpu_waves_per_eu(4, 4)))
void gateup_xb(
    const bf16* __restrict__ XB,
    const float* __restrict__ wg_, const float* __restrict__ wu_,
    const float* __restrict__ swg, const float* __restrict__ swu,
    bf16* __restrict__ act, bf16* __restrict__ acts0, bf16* __restrict__ acts1,
    const int* __restrict__ lists, const int* __restrict__ counts,
    int n_shared)
{
  int id = blockIdx.x;
  bool gather = id >= n_shared;
  const float *Wg, *Wu; const int* lb = nullptr;
  int count, mt, fb, cb, ldb, Nout; bf16* C;
  if (gather) {
    int g = id - n_shared;
    int j = g >> 3;
    int e = (g & 7) + 8 * (j / 96);   // expert e's 96 blocks share an XCD
    int rr = j % 96;
    mt = (rr / 6) * 64; fb = (rr % 6) * 128; cb = fb;
    count = counts[e]; lb = lists + e * T_TOK;
    Wg = wg_ + (size_t)e * H_DIM * F_DIM;
    Wu = wu_ + (size_t)e * H_DIM * F_DIM;
    ldb = F_DIM; Nout = F_DIM; C = act;
  } else {
    int fbi = id & 31;                // 32 fb slices of 128 over full FS
    mt = (id >> 5) * 64;
    fb = fbi * 128; cb = (fbi & 15) * 128;
    count = T_TOK; ldb = FS_DIM; Nout = FS_HALF;
    Wg = swg; Wu = swu;
    C = (fbi < 16) ? acts0 : acts1;
  }
  if (mt >= count) return;

  __shared__ alignas(16) char sA [2][64 * 64];
  __shared__ alignas(16) char sBg[2][128 * 64];
  __shared__ alignas(16) char sBu[2][128 * 64];

  int tid = threadIdx.x;
  int lane = tid & 63, wid = tid >> 6;
  int wr = wid >> 2, wc = wid & 3;   // 2x4 waves, wave tile 32m x 32n
  int l15 = lane & 15, qB = (lane >> 4) << 4;

  const bf16* aptr;
  {
    int r = mt + (tid >> 3);
    int rc = r < count ? r : count - 1;
    int tok = gather ? (lb[rc] >> 2) : rc;
    aptr = XB + (size_t)tok * H_DIM + ((tid & 7) << 2);
  }
  int t8 = tid & 255;
  int bng = t8 & 31;
  int bk4 = (t8 >> 5) << 2;
  const float* bptr = (tid < 256 ? Wg : Wu) + (size_t)bk4 * ldb + fb + bng * 4;
  char* bds = (tid < 256) ? &sBg[0][0] : &sBu[0][0];

  f32x4 accg[2][2], accu[2][2];
  #pragma unroll
  for (int m = 0; m < 2; m++)
    #pragma unroll
    for (int n = 0; n < 2; n++) {
      accg[m][n] = (f32x4){0.f,0.f,0.f,0.f};
      accu[m][n] = (f32x4){0.f,0.f,0.f,0.f};
    }

  uint2 ava, avb; f32x4 bva[4], bvb[4];

  #define GU_ISSUE(av, bv, k0) do {                                   \
    av = *(const uint2*)(aptr + (k0));                                \
    _Pragma("unroll")                                                 \
    for (int r_ = 0; r_ < 4; r_++)                                    \
      bv[r_] = *(const f32x4*)(bptr + (size_t)((k0) + r_) * ldb);     \
    __builtin_amdgcn_sched_barrier(0);                                \
  } while (0)

  #define GU_STAGE(b, av, bv) do {                                    \
    *(uint2*)(sA[b] + swz(tid >> 3, (tid & 7) << 3)) = av;            \
    _Pragma("unroll")                                                 \
    for (int i_ = 0; i_ < 4; i_++) {                                  \
      bf16x4 tb;                                                      \
      tb[0]=(bf16)bv[0][i_]; tb[1]=(bf16)bv[1][i_];                   \
      tb[2]=(bf16)bv[2][i_]; tb[3]=(bf16)bv[3][i_];                   \
      *(bf16x4*)(bds + (b) * (128 * 64) + swz(bng * 4 + i_, bk4 << 1)) = tb; \
    } } while (0)

  #define GU_MFMA(b) do {                                             \
    __builtin_amdgcn_s_setprio(1);                                    \
    bf16x8 af0 = *(const bf16x8*)(sA[b] + swz(wr * 32 + l15, qB));    \
    bf16x8 af1 = *(const bf16x8*)(sA[b] + swz(wr * 32 + 16 + l15, qB)); \
    _Pragma("unroll")                                                 \
    for (int n_ = 0; n_ < 2; n_++) {                                  \
      int rb = wc * 32 + n_ * 16 + l15;                               \
      bf16x8 bg = *(const bf16x8*)(sBg[b] + swz(rb, qB));             \
      bf16x8 bu = *(const bf16x8*)(sBu[b] + swz(rb, qB));             \
      accg[0][n_] = __builtin_amdgcn_mfma_f32_16x16x32_bf16(af0, bg, accg[0][n_], 0,0,0); \
      accg[1][n_] = __builtin_amdgcn_mfma_f32_16x16x32_bf16(af1, bg, accg[1][n_], 0,0,0); \
      accu[0][n_] = __builtin_amdgcn_mfma_f32_16x16x32_bf16(af0, bu, accu[0][n_], 0,0,0); \
      accu[1][n_] = __builtin_amdgcn_mfma_f32_16x16x32_bf16(af1, bu, accu[1][n_], 0,0,0); \
    }                                                                 \
    __builtin_amdgcn_s_setprio(0);                                    \
  } while (0)

  const int NT = H_DIM / 32;   // 64
  GU_ISSUE(ava, bva, 0);
  GU_ISSUE(avb, bvb, 32);
  GU_STAGE(0, ava, bva);
  GU_ISSUE(ava, bva, 64);
  BAR();
  for (int t = 0; t < NT; t += 2) {
    GU_MFMA(0);
    GU_STAGE(1, avb, bvb);
    if (t + 3 < NT) GU_ISSUE(avb, bvb, (t + 3) * 32);
    BAR();
    GU_MFMA(1);
    if (t + 2 < NT) {
      GU_STAGE(0, ava, bva);
      if (t + 4 < NT) GU_ISSUE(ava, bva, (t + 4) * 32);
    }
    BAR();
  }
  #undef GU_ISSUE
  #undef GU_STAGE
  #undef GU_MFMA

  #pragma unroll
  for (int m = 0; m < 2; m++) {
    #pragma unroll
    for (int q = 0; q < 4; q++) {
      int gr = mt + wr * 32 + m * 16 + (lane >> 4) * 4 + q;
      if (gr < count) {
        size_t rowo = (gather ? (size_t)lb[gr] : (size_t)gr) * Nout;
        #pragma unroll
        for (int n = 0; n < 2; n++) {
          float g = accg[m][n][q], u = accu[m][n][q];
          C[rowo + cb + wc * 32 + n * 16 + l15] =
              (bf16)(g / (1.f + __expf(-g)) * u);
        }
      }
    }
  }
}

// ------- shared-expert down-proj, full K=4096 in two phases, 64x128 tile -------
// out = sg * (acts @ swd) -- single plain store (no accumulate pass).
__global__ __launch_bounds__(256, 4) void dn_shared2(
    const bf16* __restrict__ acts0, const bf16* __restrict__ acts1,
    const float* __restrict__ swd, float* __restrict__ out,
    const float* __restrict__ sg)
{
  int id = blockIdx.x;
  int nb = (id & 15) * 128, mt = (id >> 4) * 64;

  __shared__ alignas(16) char sA[2][64 * 64];
  __shared__ alignas(16) char sB[2][128 * 64];

  int tid = threadIdx.x;
  int lane = tid & 63, wid = tid >> 6;
  int wr = wid >> 1, wc = wid & 1;
  int l15 = lane & 15, qB = (lane >> 4) << 4;
  int bng = tid & 31;
  int bk4 = (tid >> 5) << 2;

  f32x4 acc[2][4];
  #pragma unroll
  for (int m = 0; m < 2; m++)
    #pragma unroll
    for (int n = 0; n < 4; n++)
      acc[m][n] = (f32x4){0.f,0.f,0.f,0.f};

  uint4 ava, avb; f32x4 bva[4], bvb[4];

  #define DS_ISSUE(av, bv, k0) do {                                   \
    av = *(const uint4*)(aptr + (k0));                                \
    _Pragma("unroll")                                                 \
    for (int r_ = 0; r_ < 4; r_++)                                    \
      bv[r_] = *(const f32x4*)(bptr + (size_t)((k0) + r_) * H_DIM);   \
    } while (0)

  #define DS_STAGE(b, av, bv) do {                                    \
    *(uint4*)(sA[b] + swz(tid >> 2, (tid & 3) << 4)) = av;            \
    _Pragma("unroll")                                                 \
    for (int i_ = 0; i_ < 4; i_++) {                                  \
      bf16x4 tb;                                                      \
      tb[0]=(bf16)bv[0][i_]; tb[1]=(bf16)bv[1][i_];                   \
      tb[2]=(bf16)bv[2][i_]; tb[3]=(bf16)bv[3][i_];                   \
      *(bf16x4*)(sB[b] + swz(bng * 4 + i_, bk4 << 1)) = tb;           \
    } } while (0)

  #define DS_MFMA(b) do {                                             \
    __builtin_amdgcn_s_setprio(1);                                    \
    bf16x8 af0 = *(const bf16x8*)(sA[b] + swz(wr * 32 + l15, qB));    \
    bf16x8 af1 = *(const bf16x8*)(sA[b] + swz(wr * 32 + 16 + l15, qB)); \
    _Pragma("unroll")                                                 \
    for (int n_ = 0; n_ < 4; n_++) {                                  \
      bf16x8 bb = *(const bf16x8*)(sB[b] + swz(wc * 64 + n_ * 16 + l15, qB)); \
      acc[0][n_] = __builtin_amdgcn_mfma_f32_16x16x32_bf16(af0, bb, acc[0][n_], 0,0,0); \
      acc[1][n_] = __builtin_amdgcn_mfma_f32_16x16x32_bf16(af1, bb, acc[1][n_], 0,0,0); \
    }                                                                 \
    __builtin_amdgcn_s_setprio(0);                                    \
  } while (0)

  const int NT = FS_HALF / 32;   // 64
  #pragma unroll 1
  for (int p = 0; p < 2; p++) {
    const bf16* A = p ? acts1 : acts0;
    const bf16* aptr = A + (size_t)(mt + (tid >> 2)) * FS_HALF + ((tid & 3) << 3);
    const float* bptr = swd + (size_t)(p * FS_HALF + bk4) * H_DIM + nb + bng * 4;

    DS_ISSUE(ava, bva, 0);
    DS_ISSUE(avb, bvb, 32);
    DS_STAGE(0, ava, bva);
    DS_ISSUE(ava, bva, 64);
    BAR();
    for (int t = 0; t < NT; t += 2) {
      DS_MFMA(0);
      DS_STAGE(1, avb, bvb);
      if (t + 3 < NT) DS_ISSUE(avb, bvb, (t + 3) * 32);
      BAR();
      DS_MFMA(1);
      if (t + 2 < NT) {
        DS_STAGE(0, ava, bva);
        if (t + 4 < NT) DS_ISSUE(ava, bva, (t + 4) * 32);
      }
      BAR();
    }
  }
  #undef DS_ISSUE
  #undef DS_STAGE
  #undef DS_MFMA

  #pragma unroll
  for (int m = 0; m < 2; m++) {
    #pragma unroll
    for (int q = 0; q < 4; q++) {
      int gr = mt + wr * 32 + m * 16 + (lane >> 4) * 4 + q;
      #pragma unroll
      for (int n = 0; n < 4; n++) {
        int col = nb + wc * 64 + n * 16 + l15;
        out[(size_t)gr * H_DIM + col] = sg[gr] * acc[m][n][q];
      }
    }
  }
}

// ------- expert down-proj, full H, 64x128 tile (r13 engine, standalone) -------
__global__ __launch_bounds__(256, 4) void dn_expert(
    const bf16* __restrict__ act, const float* __restrict__ wd_,
    bf16* __restrict__ dslot,
    const int* __restrict__ lists, const int* __restrict__ counts)
{
  int g = blockIdx.x;
  int j = g >> 3;
  int e = (g & 7) + 8 * (j >> 7);   // expert e's 128 blocks share an XCD
  int rr = j & 127;
  int nb = (rr & 15) * 128;
  int mt = (rr >> 4) * 64;
  int count = counts[e];
  const int* lb = lists + e * T_TOK;
  if (mt >= count) return;
  const float* W = wd_ + (size_t)e * F_DIM * H_DIM;

  __shared__ alignas(16) char sA[2][64 * 64];
  __shared__ alignas(16) char sB[2][128 * 64];

  int tid = threadIdx.x;
  int lane = tid & 63, wid = tid >> 6;
  int wr = wid >> 1, wc = wid & 1;
  int l15 = lane & 15, qB = (lane >> 4) << 4;
  int bng = tid & 31;
  int bk4 = (tid >> 5) << 2;

  const bf16* aptr;
  {
    int r = mt + (tid >> 2);
    int rc = r < count ? r : count - 1;
    aptr = act + (size_t)lb[rc] * F_DIM + ((tid & 3) << 3);
  }
  const float* bptr = W + (size_t)bk4 * H_DIM + nb + bng * 4;

  f32x4 acc[2][4];
  #pragma unroll
  for (int m = 0; m < 2; m++)
    #pragma unroll
    for (int n = 0; n < 4; n++)
      acc[m][n] = (f32x4){0.f,0.f,0.f,0.f};

  uint4 ava, avb; f32x4 bva[4], bvb[4];

  #define DE_ISSUE(av, bv, k0) do {                                   \
    av = *(const uint4*)(aptr + (k0));                                \
    _Pragma("unroll")                                                 \
    for (int r_ = 0; r_ < 4; r_++)                                    \
      bv[r_] = *(const f32x4*)(bptr + (size_t)((k0) + r_) * H_DIM);   \
    } while (0)

  #define DE_STAGE(b, av, bv) do {                                    \
    *(uint4*)(sA[b] + swz(tid >> 2, (tid & 3) << 4)) = av;            \
    _Pragma("unroll")                                                 \
    for (int i_ = 0; i_ < 4; i_++) {                                  \
      bf16x4 tb;                                                      \
      tb[0]=(bf16)bv[0][i_]; tb[1]=(bf16)bv[1][i_];                   \
      tb[2]=(bf16)bv[2][i_]; tb[3]=(bf16)bv[3][i_];                   \
      *(bf16x4*)(sB[b] + swz(bng * 4 + i_, bk4 << 1)) = tb;           \
    } } while (0)

  #define DE_MFMA(b) do {                                             \
    __builtin_amdgcn_s_setprio(1);                                    \
    bf16x8 af0 = *(const bf16x8*)(sA[b] + swz(wr * 32 + l15, qB));    \
    bf16x8 af1 = *(const bf16x8*)(sA[b] + swz(wr * 32 + 16 + l15, qB)); \
    _Pragma("unroll")                                                 \
    for (int n_ = 0; n_ < 4; n_++) {                                  \
      bf16x8 bb = *(const bf16x8*)(sB[b] + swz(wc * 64 + n_ * 16 + l15, qB)); \
      acc[0][n_] = __builtin_amdgcn_mfma_f32_16x16x32_bf16(af0, bb, acc[0][n_], 0,0,0); \
      acc[1][n_] = __builtin_amdgcn_mfma_f32_16x16x32_bf16(af1, bb, acc[1][n_], 0,0,0); \
    }                                                                 \
    __builtin_amdgcn_s_setprio(0);                                    \
  } while (0)

  const int NT = F_DIM / 32;   // 24
  DE_ISSUE(ava, bva, 0);
  DE_ISSUE(avb, bvb, 32);
  DE_STAGE(0, ava, bva);
  DE_ISSUE(ava, bva, 64);
  BAR();
  for (int t = 0; t < NT; t += 2) {
    DE_MFMA(0);
    DE_STAGE(1, avb, bvb);
    if (t + 3 < NT) DE_ISSUE(avb, bvb, (t + 3) * 32);
    BAR();
    DE_MFMA(1);
    if (t + 2 < NT) {
      DE_STAGE(0, ava, bva);
      if (t + 4 < NT) DE_ISSUE(ava, bva, (t + 4) * 32);
    }
    BAR();
  }
  #undef DE_ISSUE
  #undef DE_STAGE
  #undef DE_MFMA

  #pragma unroll
  for (int m = 0; m < 2; m++) {
    #pragma unroll
    for (int q = 0; q < 4; q++) {
      int gr = mt + wr * 32 + m * 16 + (lane >> 4) * 4 + q;
      if (gr < count) {
        #pragma unroll
        for (int n = 0; n < 4; n++) {
          int col = nb + wc * 64 + n * 16 + l15;
          dslot[(size_t)lb[gr] * H_DIM + col] = (bf16)acc[m][n][q];
        }
      }
    }
  }
}

// ---------------- combine: out += sum_k topw*dslot ----------------
__global__ __launch_bounds__(256) void combine_kernel(
    const bf16* __restrict__ dslot, const float* __restrict__ topw,
    float* __restrict__ out)
{
  int t = blockIdx.x;
  int h = threadIdx.x * 8;
  float w0 = topw[t * 4 + 0], w1 = topw[t * 4 + 1];
  float w2 = topw[t * 4 + 2], w3 = topw[t * 4 + 3];
  bf16x8 a0 = *(const bf16x8*)&dslot[(size_t)(t * 4 + 0) * H_DIM + h];
  bf16x8 a1 = *(const bf16x8*)&dslot[(size_t)(t * 4 + 1) * H_DIM + h];
  bf16x8 a2 = *(const bf16x8*)&dslot[(size_t)(t * 4 + 2) * H_DIM + h];
  bf16x8 a3 = *(const bf16x8*)&dslot[(size_t)(t * 4 + 3) * H_DIM + h];
  f32x4 o0 = *(f32x4*)&out[(size_t)t * H_DIM + h];
  f32x4 o1 = *(f32x4*)&out[(size_t)t * H_DIM + h + 4];
  float o[8] = {o0[0], o0[1], o0[2], o0[3], o1[0], o1[1], o1[2], o1[3]};
  #pragma unroll
  for (int j = 0; j < 8; j++)
    o[j] += w0 * (float)a0[j] + w1 * (float)a1[j] + w2 * (float)a2[j]
          + w3 * (float)a3[j];
  *(f32x4*)&out[(size_t)t * H_DIM + h]     = (f32x4){o[0], o[1], o[2], o[3]};
  *(f32x4*)&out[(size_t)t * H_DIM + h + 4] = (f32x4){o[4], o[5], o[6], o[7]};
}

extern "C" void kernel_launch(void* const* d_in, const int* in_sizes, int n_in,
                              void* d_out, int out_size, void* d_ws, size_t ws_size,
                              hipStream_t stream) {
  const float* x   = (const float*)d_in[0];
  const float* rw  = (const float*)d_in[1];
  const float* wg  = (const float*)d_in[2];
  const float* wu  = (const float*)d_in[3];
  const float* wd  = (const float*)d_in[4];
  const float* swg = (const float*)d_in[5];
  const float* swu = (const float*)d_in[6];
  const float* swd = (const float*)d_in[7];
  const float* sgw = (const float*)d_in[8];
  float* out = (float*)d_out;
  char* ws = (char*)d_ws;

  // ws total 27.45 MB (r13-proven-safe). Aliases within dslot:
  //   xb    = dslot[0      : 4.2MB]  (dead after gateup_xb)
  //   acts1 = dslot[4.2MB  : 8.4MB]  (dead after dn_shared2)
  // dn_expert overwrites all of dslot afterwards.
  size_t off = 0;
  int*   counts = (int*)(ws + off); off += 256;
  int*   lists  = (int*)(ws + off); off += (size_t)N_EXP * T_TOK * 4;
  float* topw   = (float*)(ws + off); off += (size_t)T_TOK * TOPK * 4;
  float* sg     = (float*)(ws + off); off += (size_t)T_TOK * 4;
  bf16*  act    = (bf16*)(ws + off); off += (size_t)T_TOK * TOPK * F_DIM * 2;   // 6.3 MB
  bf16*  acts0  = (bf16*)(ws + off); off += (size_t)T_TOK * FS_HALF * 2;        // 4.2 MB
  bf16*  dslot  = (bf16*)(ws + off); off += (size_t)T_TOK * TOPK * H_DIM * 2;   // 16.8 MB
  bf16*  xb     = dslot;
  bf16*  acts1  = dslot + (size_t)T_TOK * FS_HALF;

  hipMemsetAsync(counts, 0, 256, stream);

  router_kernel<<<T_TOK, 256, 0, stream>>>(x, rw, sgw, topw, sg, counts, lists);
  xcvt_kernel<<<(T_TOK * H_DIM) / 2048, 256, 0, stream>>>(x, xb);

  const int NSH_GU = 32 * (T_TOK / 64);   // 512: full FS shared
  const int EXP_GU = N_EXP * 96;          // 3072
  const int DN_EXP = N_EXP * 128;         // 4096

  // 1. big gate/up: experts -> act, shared full FS -> acts0/acts1
  gateup_xb<<<NSH_GU + EXP_GU, 512, 0, stream>>>(
      xb, wg, wu, swg, swu, act, acts0, acts1, lists, counts, NSH_GU);
  // 2. shared down, full K (single out= store)
  dn_shared2<<<256, 256, 0, stream>>>(acts0, acts1, swd, out, sg);
  // 3. expert down -> dslot (clobbers xb/acts1, both dead)
  dn_expert<<<DN_EXP, 256, 0, stream>>>(act, wd, dslot, lists, counts);
  // 4. combine expert contributions
  combine_kernel<<<T_TOK, 256, 0, stream>>>(dslot, topw, out);
}

// Round 21
// 376.677 us; speedup vs baseline: 1.1642x; 1.0887x over previous
//
#include <hip/hip_runtime.h>
#include <math.h>

#define T_TOK 1024
#define H_DIM 2048
#define N_EXP 32
#define TOPK  4
#define F_DIM 768
#define FS_DIM 4096
#define FS_HALF 2048

typedef __bf16 bf16;
typedef __attribute__((ext_vector_type(4))) __bf16 bf16x4;
typedef __attribute__((ext_vector_type(8))) __bf16 bf16x8;
typedef __attribute__((ext_vector_type(4))) float f32x4;

// raw barrier: drain ds ops (lgkm) but let global prefetch loads stay in
// flight across the barrier; sched_barrier(0) pins code motion at the BAR.
#define BAR() do {                                        \
    asm volatile("s_waitcnt lgkmcnt(0)" ::: "memory");    \
    __builtin_amdgcn_s_barrier();                         \
    __builtin_amdgcn_sched_barrier(0);                    \
  } while (0)

// XOR-swizzled LDS offset: rows are 32 bf16 = 64B.
__device__ __forceinline__ int swz(int row, int colB) {
  return row * 64 + (colB ^ (((row >> 2) & 3) << 4));
}

// ---------------- router: fp32 logits -> softmax -> top4 -> lists ----------------
__global__ __launch_bounds__(256) void router_kernel(
    const float* __restrict__ x, const float* __restrict__ rw,
    const float* __restrict__ sgw,
    float* __restrict__ topw, float* __restrict__ sg,
    int* __restrict__ counts, int* __restrict__ lists)
{
  int t = blockIdx.x; int tid = threadIdx.x;
  int lane = tid & 63, wave = tid >> 6;
  float acc[N_EXP];
  #pragma unroll
  for (int e = 0; e < N_EXP; e++) acc[e] = 0.f;
  float accs = 0.f;
  const float* xr = x + (size_t)t * H_DIM;
  for (int h = tid; h < H_DIM; h += 256) {
    float xv = xr[h];
    accs += xv * sgw[h];
    #pragma unroll
    for (int e = 0; e < N_EXP; e++) acc[e] += xv * rw[e * H_DIM + h];
  }
  __shared__ float red[4][N_EXP];
  __shared__ float reds[4];
  __shared__ float logits[N_EXP];
  #pragma unroll
  for (int e = 0; e < N_EXP; e++) {
    float v = acc[e];
    for (int off = 32; off; off >>= 1) v += __shfl_down(v, off, 64);
    if (lane == 0) red[wave][e] = v;
  }
  {
    float v = accs;
    for (int off = 32; off; off >>= 1) v += __shfl_down(v, off, 64);
    if (lane == 0) reds[wave] = v;
  }
  __syncthreads();
  if (tid < N_EXP) logits[tid] = red[0][tid] + red[1][tid] + red[2][tid] + red[3][tid];
  __syncthreads();
  if (tid == 0) {
    float m = -1e30f;
    #pragma unroll
    for (int e = 0; e < N_EXP; e++) m = fmaxf(m, logits[e]);
    float p[N_EXP];
    #pragma unroll
    for (int e = 0; e < N_EXP; e++) p[e] = expf(logits[e] - m);
    int ids[TOPK]; float vs[TOPK]; float wsum = 0.f;
    #pragma unroll
    for (int k = 0; k < TOPK; k++) {
      int best = 0; float bv = -1.f;
      for (int e = 0; e < N_EXP; e++) {
        if (p[e] > bv) { bv = p[e]; best = e; }
      }
      ids[k] = best; vs[k] = bv; wsum += bv; p[best] = -2.f;
    }
    float inv = 1.f / wsum;
    float sgs = reds[0] + reds[1] + reds[2] + reds[3];
    sg[t] = 1.f / (1.f + expf(-sgs));
    #pragma unroll
    for (int k = 0; k < TOPK; k++) {
      int slot = t * TOPK + k;
      topw[slot] = vs[k] * inv;
      int pos = atomicAdd(&counts[ids[k]], 1);
      lists[ids[k] * T_TOK + pos] = slot;
    }
  }
}

// ------- fused gate/up dual GEMM + SwiGLU, 64x128 tile, BK=32, 512 threads -------
// 8 waves (2x4), wave tile 32x32. Threads 0-255 stage Wg, 256-511 stage Wu.
// 2-deep register prefetch, swizzled LDS, one raw barrier per K-step.
__global__ __launch_bounds__(512) __attribute__((amdgpu_waves_per_eu(4, 4)))
void gateup_fused(
    const float* __restrict__ X,
    const float* __restrict__ wg_, const float* __restrict__ wu_,
    const float* __restrict__ swg, const float* __restrict__ swu,
    bf16* __restrict__ act, bf16* __restrict__ acts,
    const int* __restrict__ lists, const int* __restrict__ counts,
    int n_shared, int sh_nfb, int actsN, int col_off)
{
  int id = blockIdx.x;
  bool gather = id >= n_shared;
  const float *Wg, *Wu; const int* lb = nullptr;
  int count, mt, fb, ldb, Nout; bf16* C;
  if (gather) {
    int g = id - n_shared;
    int j = g >> 3;
    int e = (g & 7) + 8 * (j / 96);   // expert e's 96 blocks share an XCD
    int rr = j % 96;
    mt = (rr / 6) * 64; fb = (rr % 6) * 128;
    count = counts[e]; lb = lists + e * T_TOK;
    Wg = wg_ + (size_t)e * H_DIM * F_DIM;
    Wu = wu_ + (size_t)e * H_DIM * F_DIM;
    ldb = F_DIM; Nout = F_DIM; C = act;
  } else {
    fb = (id % sh_nfb) * 128; mt = (id / sh_nfb) * 64;
    count = T_TOK; ldb = FS_DIM; Nout = actsN;
    Wg = swg + col_off; Wu = swu + col_off;
    C = acts;
  }
  if (mt >= count) return;

  __shared__ alignas(16) char sA [2][64 * 64];
  __shared__ alignas(16) char sBg[2][128 * 64];
  __shared__ alignas(16) char sBu[2][128 * 64];

  int tid = threadIdx.x;
  int lane = tid & 63, wid = tid >> 6;
  int wr = wid >> 2, wc = wid & 3;   // 2x4 waves, wave tile 32m x 32n
  int l15 = lane & 15, qB = (lane >> 4) << 4;

  const float* aptr;
  {
    int r = mt + (tid >> 3);
    int rc = r < count ? r : count - 1;
    int tok = gather ? (lb[rc] >> 2) : rc;
    aptr = X + (size_t)tok * H_DIM + ((tid & 7) << 2);
  }
  int t8 = tid & 255;
  int bng = t8 & 31;
  int bk4 = (t8 >> 5) << 2;
  const float* bptr = (tid < 256 ? Wg : Wu) + (size_t)bk4 * ldb + fb + bng * 4;
  char* bds = (tid < 256) ? &sBg[0][0] : &sBu[0][0];

  f32x4 accg[2][2], accu[2][2];
  #pragma unroll
  for (int m = 0; m < 2; m++)
    #pragma unroll
    for (int n = 0; n < 2; n++) {
      accg[m][n] = (f32x4){0.f,0.f,0.f,0.f};
      accu[m][n] = (f32x4){0.f,0.f,0.f,0.f};
    }

  f32x4 ava, bva[4];    // prefetch set A
  f32x4 avb, bvb[4];    // prefetch set B

  #define GU_ISSUE(av, bv, k0) do {                                   \
    av = *(const f32x4*)(aptr + (k0));                                \
    _Pragma("unroll")                                                 \
    for (int r_ = 0; r_ < 4; r_++)                                    \
      bv[r_] = *(const f32x4*)(bptr + (size_t)((k0) + r_) * ldb);     \
    __builtin_amdgcn_sched_barrier(0);                                \
  } while (0)

  #define GU_STAGE(b, av, bv) do {                                    \
    bf16x4 ta;                                                        \
    ta[0]=(bf16)av[0]; ta[1]=(bf16)av[1];                             \
    ta[2]=(bf16)av[2]; ta[3]=(bf16)av[3];                             \
    *(bf16x4*)(sA[b] + swz(tid >> 3, (tid & 7) << 3)) = ta;           \
    _Pragma("unroll")                                                 \
    for (int i_ = 0; i_ < 4; i_++) {                                  \
      bf16x4 tb;                                                      \
      tb[0]=(bf16)bv[0][i_]; tb[1]=(bf16)bv[1][i_];                   \
      tb[2]=(bf16)bv[2][i_]; tb[3]=(bf16)bv[3][i_];                   \
      *(bf16x4*)(bds + (b) * (128 * 64) + swz(bng * 4 + i_, bk4 << 1)) = tb; \
    } } while (0)

  #define GU_MFMA(b) do {                                             \
    __builtin_amdgcn_s_setprio(1);                                    \
    bf16x8 af0 = *(const bf16x8*)(sA[b] + swz(wr * 32 + l15, qB));    \
    bf16x8 af1 = *(const bf16x8*)(sA[b] + swz(wr * 32 + 16 + l15, qB)); \
    _Pragma("unroll")                                                 \
    for (int n_ = 0; n_ < 2; n_++) {                                  \
      int rb = wc * 32 + n_ * 16 + l15;                               \
      bf16x8 bg = *(const bf16x8*)(sBg[b] + swz(rb, qB));             \
      bf16x8 bu = *(const bf16x8*)(sBu[b] + swz(rb, qB));             \
      accg[0][n_] = __builtin_amdgcn_mfma_f32_16x16x32_bf16(af0, bg, accg[0][n_], 0,0,0); \
      accg[1][n_] = __builtin_amdgcn_mfma_f32_16x16x32_bf16(af1, bg, accg[1][n_], 0,0,0); \
      accu[0][n_] = __builtin_amdgcn_mfma_f32_16x16x32_bf16(af0, bu, accu[0][n_], 0,0,0); \
      accu[1][n_] = __builtin_amdgcn_mfma_f32_16x16x32_bf16(af1, bu, accu[1][n_], 0,0,0); \
    }                                                                 \
    __builtin_amdgcn_s_setprio(0);                                    \
  } while (0)

  const int NT = H_DIM / 32;   // 64
  GU_ISSUE(ava, bva, 0);
  GU_ISSUE(avb, bvb, 32);
  GU_STAGE(0, ava, bva);
  GU_ISSUE(ava, bva, 64);
  BAR();
  for (int t = 0; t < NT; t += 2) {
    GU_MFMA(0);
    GU_STAGE(1, avb, bvb);
    if (t + 3 < NT) GU_ISSUE(avb, bvb, (t + 3) * 32);
    BAR();
    GU_MFMA(1);
    if (t + 2 < NT) {
      GU_STAGE(0, ava, bva);
      if (t + 4 < NT) GU_ISSUE(ava, bva, (t + 4) * 32);
    }
    BAR();
  }
  #undef GU_ISSUE
  #undef GU_STAGE
  #undef GU_MFMA

  #pragma unroll
  for (int m = 0; m < 2; m++) {
    #pragma unroll
    for (int q = 0; q < 4; q++) {
      int gr = mt + wr * 32 + m * 16 + (lane >> 4) * 4 + q;
      if (gr < count) {
        size_t rowo = (gather ? (size_t)lb[gr] : (size_t)gr) * Nout;
        #pragma unroll
        for (int n = 0; n < 2; n++) {
          float g = accg[m][n][q], u = accu[m][n][q];
          C[rowo + fb + wc * 32 + n * 16 + l15] =
              (bf16)(g / (1.f + __expf(-g)) * u);
        }
      }
    }
  }
}

// ------- fused down-proj, 64x128 tile, BK=32, 2-deep prefetch -------
__global__ __launch_bounds__(256, 4) void down_fused(
    const bf16* __restrict__ act, const bf16* __restrict__ acts,
    const float* __restrict__ wd_, const float* __restrict__ swd,
    bf16* __restrict__ dslot, float* __restrict__ out,
    const float* __restrict__ sg,
    const int* __restrict__ lists, const int* __restrict__ counts,
    int n_shared, int lda_sh, int kd_sh, int swd_off, int accum)
{
  int id = blockIdx.x;
  bool expert = id >= n_shared;
  const bf16* A; const float* W; const int* lb = nullptr;
  int count, mt, nb, Kd, lda;
  if (expert) {
    int g = id - n_shared;
    int j = g >> 3;
    int e = (g & 7) + 8 * (j >> 7);   // expert e's 128 blocks share an XCD
    int rr = j & 127;
    nb = (rr & 15) * 128; mt = (rr >> 4) * 64;
    count = counts[e]; lb = lists + e * T_TOK;
    A = act; lda = F_DIM; Kd = F_DIM;
    W = wd_ + (size_t)e * F_DIM * H_DIM;
  } else {
    nb = (id & 15) * 128; mt = (id >> 4) * 64;
    count = T_TOK; A = acts; lda = lda_sh; Kd = kd_sh;
    W = swd + (size_t)swd_off * H_DIM;
  }
  if (mt >= count) return;

  __shared__ alignas(16) char sA[2][64 * 64];
  __shared__ alignas(16) char sB[2][128 * 64];

  int tid = threadIdx.x;
  int lane = tid & 63, wid = tid >> 6;
  int wr = wid >> 1, wc = wid & 1;
  int l15 = lane & 15, qB = (lane >> 4) << 4;
  int bng = tid & 31;
  int bk4 = (tid >> 5) << 2;

  const bf16* aptr;
  {
    int r = mt + (tid >> 2);
    int rc = r < count ? r : count - 1;
    int ar = expert ? lb[rc] : rc;
    aptr = A + (size_t)ar * lda + ((tid & 3) << 3);
  }
  const float* bptr = W + (size_t)bk4 * H_DIM + nb + bng * 4;

  f32x4 acc[2][4];
  #pragma unroll
  for (int m = 0; m < 2; m++)
    #pragma unroll
    for (int n = 0; n < 4; n++)
      acc[m][n] = (f32x4){0.f,0.f,0.f,0.f};

  uint4 ava, avb; f32x4 bva[4], bvb[4];

  #define DN_ISSUE(av, bv, k0) do {                                   \
    av = *(const uint4*)(aptr + (k0));                                \
    _Pragma("unroll")                                                 \
    for (int r_ = 0; r_ < 4; r_++)                                    \
      bv[r_] = *(const f32x4*)(bptr + (size_t)((k0) + r_) * H_DIM);   \
    } while (0)

  #define DN_STAGE(b, av, bv) do {                                    \
    *(uint4*)(sA[b] + swz(tid >> 2, (tid & 3) << 4)) = av;            \
    _Pragma("unroll")                                                 \
    for (int i_ = 0; i_ < 4; i_++) {                                  \
      bf16x4 tb;                                                      \
      tb[0]=(bf16)bv[0][i_]; tb[1]=(bf16)bv[1][i_];                   \
      tb[2]=(bf16)bv[2][i_]; tb[3]=(bf16)bv[3][i_];                   \
      *(bf16x4*)(sB[b] + swz(bng * 4 + i_, bk4 << 1)) = tb;           \
    } } while (0)

  #define DN_MFMA(b) do {                                             \
    __builtin_amdgcn_s_setprio(1);                                    \
    bf16x8 af0 = *(const bf16x8*)(sA[b] + swz(wr * 32 + l15, qB));    \
    bf16x8 af1 = *(const bf16x8*)(sA[b] + swz(wr * 32 + 16 + l15, qB)); \
    _Pragma("unroll")                                                 \
    for (int n_ = 0; n_ < 4; n_++) {                                  \
      bf16x8 bb = *(const bf16x8*)(sB[b] + swz(wc * 64 + n_ * 16 + l15, qB)); \
      acc[0][n_] = __builtin_amdgcn_mfma_f32_16x16x32_bf16(af0, bb, acc[0][n_], 0,0,0); \
      acc[1][n_] = __builtin_amdgcn_mfma_f32_16x16x32_bf16(af1, bb, acc[1][n_], 0,0,0); \
    }                                                                 \
    __builtin_amdgcn_s_setprio(0);                                    \
  } while (0)

  const int NT = Kd / 32;   // 24 or 64 (even)
  DN_ISSUE(ava, bva, 0);
  DN_ISSUE(avb, bvb, 32);
  DN_STAGE(0, ava, bva);
  DN_ISSUE(ava, bva, 64);
  BAR();
  for (int t = 0; t < NT; t += 2) {
    DN_MFMA(0);
    DN_STAGE(1, avb, bvb);
    if (t + 3 < NT) DN_ISSUE(avb, bvb, (t + 3) * 32);
    BAR();
    DN_MFMA(1);
    if (t + 2 < NT) {
      DN_STAGE(0, ava, bva);
      if (t + 4 < NT) DN_ISSUE(ava, bva, (t + 4) * 32);
    }
    BAR();
  }
  #undef DN_ISSUE
  #undef DN_STAGE
  #undef DN_MFMA

  #pragma unroll
  for (int m = 0; m < 2; m++) {
    #pragma unroll
    for (int q = 0; q < 4; q++) {
      int gr = mt + wr * 32 + m * 16 + (lane >> 4) * 4 + q;
      if (gr < count) {
        #pragma unroll
        for (int n = 0; n < 4; n++) {
          int col = nb + wc * 64 + n * 16 + l15;
          if (expert) {
            dslot[(size_t)lb[gr] * H_DIM + col] = (bf16)acc[m][n][q];
          } else if (!accum) {
            out[(size_t)gr * H_DIM + col] = sg[gr] * acc[m][n][q];
          } else {
            out[(size_t)gr * H_DIM + col] += sg[gr] * acc[m][n][q];
          }
        }
      }
    }
  }
}

// ---------------- combine: out += sum_k topw*dslot ----------------
__global__ __launch_bounds__(256) void combine_kernel(
    const bf16* __restrict__ dslot, const float* __restrict__ topw,
    float* __restrict__ out)
{
  int t = blockIdx.x;
  int h = threadIdx.x * 8;
  float w0 = topw[t * 4 + 0], w1 = topw[t * 4 + 1];
  float w2 = topw[t * 4 + 2], w3 = topw[t * 4 + 3];
  bf16x8 a0 = *(const bf16x8*)&dslot[(size_t)(t * 4 + 0) * H_DIM + h];
  bf16x8 a1 = *(const bf16x8*)&dslot[(size_t)(t * 4 + 1) * H_DIM + h];
  bf16x8 a2 = *(const bf16x8*)&dslot[(size_t)(t * 4 + 2) * H_DIM + h];
  bf16x8 a3 = *(const bf16x8*)&dslot[(size_t)(t * 4 + 3) * H_DIM + h];
  f32x4 o0 = *(f32x4*)&out[(size_t)t * H_DIM + h];
  f32x4 o1 = *(f32x4*)&out[(size_t)t * H_DIM + h + 4];
  float o[8] = {o0[0], o0[1], o0[2], o0[3], o1[0], o1[1], o1[2], o1[3]};
  #pragma unroll
  for (int j = 0; j < 8; j++)
    o[j] += w0 * (float)a0[j] + w1 * (float)a1[j] + w2 * (float)a2[j]
          + w3 * (float)a3[j];
  *(f32x4*)&out[(size_t)t * H_DIM + h]     = (f32x4){o[0], o[1], o[2], o[3]};
  *(f32x4*)&out[(size_t)t * H_DIM + h + 4] = (f32x4){o[4], o[5], o[6], o[7]};
}

extern "C" void kernel_launch(void* const* d_in, const int* in_sizes, int n_in,
                              void* d_out, int out_size, void* d_ws, size_t ws_size,
                              hipStream_t stream) {
  const float* x   = (const float*)d_in[0];
  const float* rw  = (const float*)d_in[1];
  const float* wg  = (const float*)d_in[2];
  const float* wu  = (const float*)d_in[3];
  const float* wd  = (const float*)d_in[4];
  const float* swg = (const float*)d_in[5];
  const float* swu = (const float*)d_in[6];
  const float* swd = (const float*)d_in[7];
  const float* sgw = (const float*)d_in[8];
  float* out = (float*)d_out;
  char* ws = (char*)d_ws;

  // ws total ~27.45 MB (proven-safe; 34 MB overflowed in round 3)
  bool fullfs = ws_size >= (size_t)32000000;
  size_t actsN = fullfs ? FS_DIM : FS_HALF;
  int sh_nfb = (int)(actsN / 128);   // 32 or 16
  int nsh_gu = sh_nfb * (T_TOK / 64);

  size_t off = 0;
  int*   counts  = (int*)(ws + off); off += 256;
  int*   lists   = (int*)(ws + off); off += (size_t)N_EXP * T_TOK * 4;
  float* topw    = (float*)(ws + off); off += (size_t)T_TOK * TOPK * 4;
  float* sg      = (float*)(ws + off); off += (size_t)T_TOK * 4;
  bf16*  act     = (bf16*)(ws + off); off += (size_t)T_TOK * TOPK * F_DIM * 2;
  bf16*  acts    = (bf16*)(ws + off); off += (size_t)T_TOK * actsN * 2;
  bf16*  dslot   = (bf16*)(ws + off); off += (size_t)T_TOK * TOPK * H_DIM * 2;

  hipMemsetAsync(counts, 0, 256, stream);

  router_kernel<<<T_TOK, 256, 0, stream>>>(x, rw, sgw, topw, sg, counts, lists);

  const int EXP_GU = N_EXP * 96;    // 3072 (full mt coverage, early-exit)
  const int DN_EXP = N_EXP * 128;   // 4096

  if (fullfs) {
    gateup_fused<<<nsh_gu + EXP_GU, 512, 0, stream>>>(
        x, wg, wu, swg, swu, act, acts, lists, counts,
        nsh_gu, sh_nfb, FS_DIM, 0);
    down_fused<<<256 + DN_EXP, 256, 0, stream>>>(
        act, acts, wd, swd, dslot, out, sg, lists, counts,
        256, FS_DIM, FS_DIM, 0, 0);
  } else {
    gateup_fused<<<nsh_gu + EXP_GU, 512, 0, stream>>>(
        x, wg, wu, swg, swu, act, acts, lists, counts,
        nsh_gu, sh_nfb, FS_HALF, 0);
    down_fused<<<256 + DN_EXP, 256, 0, stream>>>(
        act, acts, wd, swd, dslot, out, sg, lists, counts,
        256, FS_HALF, FS_HALF, 0, 0);
    // second half of shared expert: grid = nsh_gu -> all blocks are shared
    gateup_fused<<<nsh_gu, 512, 0, stream>>>(
        x, wg, wu, swg, swu, act, acts, lists, counts,
        nsh_gu, sh_nfb, FS_HALF, FS_HALF);
    down_fused<<<256, 256, 0, stream>>>(
        act, acts, wd, swd, dslot, out, sg, lists, counts,
        256, FS_HALF, FS_HALF, FS_HALF, 1);
  }
  combine_kernel<<<T_TOK, 256, 0, stream>>>(dslot, topw, out);
}